// Round 8
// baseline (322.293 us; speedup 1.0000x reference)
//
#include <hip/hip_runtime.h>
#include <cstdint>
#include <cmath>

#define BB   4
#define NK   4000
#define NKP  (BB*NK)      // 16000 keypoints total
#define CH   128
#define HH   240
#define WW   320
#define HWSZ (HH*WW)
#define NPOS 8

typedef __attribute__((ext_vector_type(8))) short short8;
typedef __attribute__((ext_vector_type(8))) unsigned short ushort8;
typedef __attribute__((ext_vector_type(4))) float f32x4;

// ws layout (bytes):
//   sfT      : 65,536  @ 65,536,000  [legacy]
//   w1T      : 73,728  @ 65,601,536
//   xclb     : bf16 NHWC x, 78,643,200 @ 65,675,264
//   sfB      : 32,768  @ 222,961,664  [bf16 MFMA-packed sf_w^T]
//   agB      : 262,144 @ 222,994,432  [bf16 MFMA-packed agg_w]
static constexpr size_t OFF_POS  = 32768000;
static constexpr size_t OFF_SFT  = 65536000;
static constexpr size_t OFF_W1T  = 65601536;
static constexpr size_t OFF_XCL  = 65675264;
static constexpr size_t OFF_SFB  = 222961664;
static constexpr size_t OFF_AGB  = 222994432;
static constexpr size_t WS_FULL  = 223256576;
static constexpr size_t WS_MIN   = 65675264;

__device__ __forceinline__ unsigned short f2bf(float f) {   // RNE
    unsigned int u = __float_as_uint(f);
    u += 0x7fff + ((u >> 16) & 1);
    return (unsigned short)(u >> 16);
}
__device__ __forceinline__ float bf2f(unsigned short u) {
    return __uint_as_float((unsigned)u << 16);
}

// ---------------- K0: weight prep ----------------
__global__ __launch_bounds__(256) void k_prep(const float* __restrict__ sfw,
                                              const float* __restrict__ w1,
                                              const float* __restrict__ aggw,
                                              float* __restrict__ sfT,
                                              float* __restrict__ w1T,
                                              unsigned short* __restrict__ sfB,
                                              unsigned short* __restrict__ agB)
{
    int id = blockIdx.x * 256 + threadIdx.x;   // 182272 total
    if (id < 16384) {
        int cc = id >> 7, dd = id & 127;
        sfT[cc * 128 + dd] = sfw[dd * 128 + cc];
    } else if (id < 16384 + 18432) {
        int j = id - 16384;
        int o = j / 1152, r = j % 1152;
        int k = r >> 7, c = r & 127;
        w1T[j] = w1[o * 1152 + c * 9 + k];
    } else if (id < 16384 + 18432 + 16384) {
        int idx = id - (16384 + 18432);
        int j = idx & 7, lane = (idx >> 3) & 63, nt = (idx >> 9) & 7, kc32 = (idx >> 12) & 3;
        int k = kc32 * 32 + (lane >> 4) * 8 + j;
        int n = nt * 16 + (lane & 15);
        sfB[idx] = f2bf(sfw[n * 128 + k]);     // B[c][d] = sf_w[d][c]
    } else if (id < 16384 + 18432 + 16384 + 131072) {
        int idx = id - (16384 + 18432 + 16384);
        int local = idx & 16383, kc = idx >> 14;
        int j = local & 7, lane = (local >> 3) & 63, nt = (local >> 9) & 7, kc32 = (local >> 12) & 3;
        int k = kc * 128 + kc32 * 32 + (lane >> 4) * 8 + j;
        int n = nt * 16 + (lane & 15);
        agB[idx] = f2bf(aggw[(size_t)k * 128 + n]);
    }
}

// ---------------- K0b: NCHW fp32 -> NHWC bf16, 128ch x 64px tile ----------------
// k_tr is closed: 4 structural theories falsified (coalescing width, occupancy,
// rd/wr overlap, XCD remap); only byte-halving (bf16) moved it. ~62 us floor.
__global__ __launch_bounds__(256) void k_tr(const float* __restrict__ x,
                                            unsigned short* __restrict__ xclb)
{
    const int b  = blockIdx.y;
    const int p0 = blockIdx.x * 64;
    const int t  = threadIdx.x;
    __shared__ float tile[64 * 129];

    #pragma unroll
    for (int i = 0; i < 8; ++i) {
        int flat = i * 256 + t;          // 0..2047
        int c  = flat >> 4;              // 0..127
        int p4 = flat & 15;              // 0..15
        float4 v = *(const float4*)(x + ((size_t)(b * 128 + c)) * HWSZ + p0 + p4 * 4);
        tile[(p4 * 4 + 0) * 129 + c] = v.x;
        tile[(p4 * 4 + 1) * 129 + c] = v.y;
        tile[(p4 * 4 + 2) * 129 + c] = v.z;
        tile[(p4 * 4 + 3) * 129 + c] = v.w;
    }
    __syncthreads();
    #pragma unroll
    for (int j = 0; j < 4; ++j) {
        int flat = j * 256 + t;          // 0..1023
        int p  = flat >> 4;              // 0..63
        int c8 = flat & 15;              // 0..15
        ushort8 o;
        #pragma unroll
        for (int k = 0; k < 8; ++k)
            o[k] = f2bf(tile[p * 129 + c8 * 8 + k]);
        *(ushort8*)(xclb + ((size_t)b * HWSZ + p0 + p) * CH + c8 * 8) = o;
    }
}

// ---------------- K1: mega-fused keypoint pipeline ----------------
// 16 kp / block, grid 1000. Phases (all block-local, no HBM intermediates):
//   A: 3x3 offset conv + MLP -> posl (LDS)   [cxy precomputed in LDS: staging
//      is LDS-read -> load, not kp-load -> convert -> load (2 chained latencies)]
//   B: bilinear gather -> As -> sf MFMA -> selu -> Gl (swizzled)
//      [T14 issue-early: all 32 corner loads (8 samples x 4) batched into
//       rv[8][4] regs before any interpolation -- r4 VGPR=68 proved the
//       compiler wasn't batching; MLP was ~4 loads in flight at 200-500cy]
//   C: agg MFMA (K=1024) -> L2 normalize -> out
// LDS < 54613 B (160KiB/3) -> 3 blocks/CU.
__global__ __launch_bounds__(256) void k_mega(
    const unsigned short* __restrict__ xclb, const float* __restrict__ kp,
    const float* __restrict__ w1T, const float* __restrict__ b1,
    const float* __restrict__ w2,  const float* __restrict__ b2,
    const unsigned short* __restrict__ sfB,
    const unsigned short* __restrict__ agB,
    float* __restrict__ out)
{
    const int t  = threadIdx.x;
    const int n0 = blockIdx.x * 16;
    const int bi = n0 / NK;              // uniform per block (NK % 16 == 0)

    __shared__ __align__(16) char U[49664];
    float* wl = (float*)U;                       // [16*388] f32   (A)
    float* pl = (float*)(U + 24832);             // [16*388] f32   (A)
    char*  AsB = U;                              // [64 rows x 256B]  bf16 (B)
    char*  GlB = U + 16384;                      // [128 rows x 256B] bf16 (B,C)
    float* Dl = (float*)U;                       // [16*132] f32   (C)
    __shared__ float  o1l[16 * 16];
    __shared__ float  kwl[16 * 2];
    __shared__ int2   cxyl[16];
    __shared__ float2 posl[128];

    // ================= phase A: offset conv + MLP =================
    if (t < 16) {
        const int n = n0 + t;
        float kx = kp[2 * n], ky = kp[2 * n + 1];
        float kwx = (kx * 0.5f + 0.5f) * (float)(WW - 1);
        float kwy = (ky * 0.5f + 0.5f) * (float)(HH - 1);
        kwl[t * 2 + 0] = kwx;
        kwl[t * 2 + 1] = kwy;
        int cx = (int)((float)((int)kwx) - 0.5f);
        int cy = (int)((float)((int)kwy) - 0.5f);
        cx = min(max(cx, 0), WW - 4);
        cy = min(max(cy, 0), HH - 4);
        cxyl[t] = make_int2(cx, cy);
    }
    __syncthreads();

    const int o_c  = t >> 4;
    const int kp_c = t & 15;
    float acc0 = 0.f, acc1 = 0.f;
    const unsigned short* xb = xclb + (size_t)bi * HWSZ * CH;

    for (int h = 0; h < 3; ++h) {
        if (h) __syncthreads();
        #pragma unroll
        for (int i = 0; i < 6; ++i) {
            int idx = i * 256 + t;
            int o = idx / 96, c4 = idx % 96;
            *(float4*)&wl[o * 388 + c4 * 4] =
                *(const float4*)&w1T[o * 1152 + h * 384 + c4 * 4];
        }
        #pragma unroll
        for (int i = 0; i < 3; ++i) {
            int idx = i * 256 + t;       // 0..767
            int kk = idx / 48, r = idx % 48;
            int px = r >> 4, c8 = r & 15;
            int2 c = cxyl[kk];
            ushort8 raw = *(const ushort8*)(xb + ((size_t)(c.y + h) * WW + (c.x + px)) * CH + c8 * 8);
            float* dst = &pl[kk * 388 + px * 128 + c8 * 8];
            #pragma unroll
            for (int k = 0; k < 8; ++k) dst[k] = bf2f(raw[k]);
        }
        __syncthreads();
        #pragma unroll 4
        for (int q = 0; q < 96; q += 2) {
            float4 w0 = *(const float4*)&wl[o_c * 388 + q * 4];
            float4 p0 = *(const float4*)&pl[kp_c * 388 + q * 4];
            float4 w1v = *(const float4*)&wl[o_c * 388 + q * 4 + 4];
            float4 p1 = *(const float4*)&pl[kp_c * 388 + q * 4 + 4];
            acc0 = fmaf(w0.x, p0.x, fmaf(w0.y, p0.y, fmaf(w0.z, p0.z, fmaf(w0.w, p0.w, acc0))));
            acc1 = fmaf(w1v.x, p1.x, fmaf(w1v.y, p1.y, fmaf(w1v.z, p1.z, fmaf(w1v.w, p1.w, acc1))));
        }
    }

    __syncthreads();
    o1l[kp_c * 16 + o_c] = fmaxf(acc0 + acc1 + b1[o_c], 0.f);
    __syncthreads();

    if (t < 128) {
        const int kk = t >> 3, j = t & 7;
        float sx = b2[j], sy = b2[8 + j];
        #pragma unroll
        for (int i = 0; i < 16; ++i) {
            float v = o1l[kk * 16 + i];
            sx = fmaf(v, w2[j * 16 + i], sx);
            sy = fmaf(v, w2[(8 + j) * 16 + i], sy);
        }
        sx = fminf(fmaxf(sx, -80.f), 80.f);
        sy = fminf(fmaxf(sy, -80.f), 80.f);
        posl[kk * 8 + j] = make_float2(kwl[kk * 2 + 0] + sx, kwl[kk * 2 + 1] + sy);
    }
    __syncthreads();

    // ================= phase B: gather + sf MFMA + selu -> Gl =================
    const int w = t >> 6, l = t & 63;
    const int fr = l & 15, fq = l >> 4;
    const int grp = t >> 5, lane32 = t & 31;

    for (int chunk = 0; chunk < 2; ++chunk) {
        if (chunk) __syncthreads();      // As reads of prev chunk complete

        // --- issue all 32 corner loads first (8 samples x 4 corners) ---
        ushort4 rv[8][4];
        #pragma unroll
        for (int it = 0; it < 8; ++it) {
            const int r = it * 8 + grp;  // As row 0..63
            float2 P = posl[chunk * 64 + r];
            const float x0 = floorf(P.x), y0 = floorf(P.y);
            #pragma unroll
            for (int dy = 0; dy < 2; ++dy) {
                const float yc = y0 + (float)dy;
                const int  yi = (int)fminf(fmaxf(yc, 0.f), (float)(HH - 1));
                #pragma unroll
                for (int dx = 0; dx < 2; ++dx) {
                    const float xc = x0 + (float)dx;
                    const int  xi = (int)fminf(fmaxf(xc, 0.f), (float)(WW - 1));
                    rv[it][dy * 2 + dx] =
                        *(const ushort4*)(xb + ((size_t)yi * WW + xi) * CH + lane32 * 4);
                }
            }
        }
        // --- consume: interpolate + bf16 + swizzled store to As ---
        #pragma unroll
        for (int it = 0; it < 8; ++it) {
            const int r = it * 8 + grp;
            float2 P = posl[chunk * 64 + r];
            const float x0 = floorf(P.x), y0 = floorf(P.y);
            const float wx = P.x - x0, wy = P.y - y0;
            float4 acc = {0.f, 0.f, 0.f, 0.f};
            #pragma unroll
            for (int dy = 0; dy < 2; ++dy) {
                const float yc = y0 + (float)dy;
                const bool vy = (yc >= 0.f) && (yc <= (float)(HH - 1));
                const float wyv = dy ? wy : (1.f - wy);
                #pragma unroll
                for (int dx = 0; dx < 2; ++dx) {
                    const float xc = x0 + (float)dx;
                    const bool vx = (xc >= 0.f) && (xc <= (float)(WW - 1));
                    const float wgt = (vx && vy) ? (dx ? wx : (1.f - wx)) * wyv : 0.f;
                    ushort4 q = rv[it][dy * 2 + dx];
                    acc.x = fmaf(bf2f(q.x), wgt, acc.x);
                    acc.y = fmaf(bf2f(q.y), wgt, acc.y);
                    acc.z = fmaf(bf2f(q.z), wgt, acc.z);
                    acc.w = fmaf(bf2f(q.w), wgt, acc.w);
                }
            }
            ushort4 o = {f2bf(acc.x), f2bf(acc.y), f2bf(acc.z), f2bf(acc.w)};
            unsigned byte = (unsigned)(r * 256 + lane32 * 8);
            byte ^= ((unsigned)(r & 7)) << 4;
            *(ushort4*)(AsB + byte) = o;
        }
        __syncthreads();

        short8 a[4];
        #pragma unroll
        for (int q = 0; q < 4; ++q) {
            const int row = w * 16 + fr;
            unsigned byte = (unsigned)(row * 256 + q * 64 + fq * 16);
            byte ^= ((unsigned)(row & 7)) << 4;
            a[q] = *(const short8*)(AsB + byte);
        }

        f32x4 acc[8];
        #pragma unroll
        for (int nt = 0; nt < 8; ++nt)
            #pragma unroll
            for (int r = 0; r < 4; ++r) acc[nt][r] = 0.f;

        #pragma unroll 2
        for (int nt = 0; nt < 8; ++nt) {
            short8 b[4];
            #pragma unroll
            for (int q = 0; q < 4; ++q)
                b[q] = *(const short8*)(sfB + ((size_t)(q * 8 + nt) * 64 + l) * 8);
            #pragma unroll
            for (int q = 0; q < 4; ++q)
                acc[nt] = __builtin_amdgcn_mfma_f32_16x16x32_bf16(a[q], b[q], acc[nt], 0, 0, 0);
        }

        #pragma unroll
        for (int nt = 0; nt < 8; ++nt)
            #pragma unroll
            for (int r = 0; r < 4; ++r) {
                float v = acc[nt][r];
                // selu; __expf ok: result rounded to bf16 (quantum ~4e-3 rel).
                float e = v > 0.f ? v : 1.6732632423543772f * (__expf(v) - 1.f);
                const int row = chunk * 64 + w * 16 + fq * 4 + r;
                unsigned byte = (unsigned)(row * 256 + (nt * 16 + fr) * 2);
                byte ^= ((unsigned)((row >> 3) & 7)) << 4;
                *(unsigned short*)(GlB + byte) = f2bf(1.0507009873554805f * e);
            }
    }
    __syncthreads();

    // ================= phase C: agg MFMA + normalize =================
    f32x4 acc2[2];
    #pragma unroll
    for (int i = 0; i < 2; ++i)
        #pragma unroll
        for (int r = 0; r < 4; ++r) acc2[i][r] = 0.f;

    const int nt0 = w * 2;
    #pragma unroll 4
    for (int kk = 0; kk < 32; ++kk) {
        const int row = fr * 8 + (kk >> 2);            // n_local*8 + p
        unsigned byte = (unsigned)(row * 256 + ((kk & 3) * 32 + fq * 8) * 2);
        byte ^= ((unsigned)((row >> 3) & 7)) << 4;
        short8 a2 = *(const short8*)(GlB + byte);
        #pragma unroll
        for (int i = 0; i < 2; ++i) {
            short8 b2 = *(const short8*)(agB + (size_t)(kk >> 2) * 16384 +
                ((size_t)(((kk & 3) * 8 + nt0 + i) * 64 + l)) * 8);
            acc2[i] = __builtin_amdgcn_mfma_f32_16x16x32_bf16(a2, b2, acc2[i], 0, 0, 0);
        }
    }

    #pragma unroll
    for (int i = 0; i < 2; ++i)
        #pragma unroll
        for (int r = 0; r < 4; ++r)
            Dl[(fq * 4 + r) * 132 + w * 32 + i * 16 + fr] = acc2[i][r];
    __syncthreads();

    {
        const int row = t >> 4, seg = t & 15;
        const float* dr = Dl + row * 132 + seg * 8;
        float4 d0 = *(const float4*)(dr);
        float4 d1 = *(const float4*)(dr + 4);
        float s = d0.x*d0.x + d0.y*d0.y + d0.z*d0.z + d0.w*d0.w
                + d1.x*d1.x + d1.y*d1.y + d1.z*d1.z + d1.w*d1.w;
        #pragma unroll
        for (int m = 1; m < 16; m <<= 1) s += __shfl_xor(s, m);
        const float inv = 1.f / fmaxf(sqrtf(s), 1e-12f);
        float* op = out + (size_t)(n0 + row) * 128 + seg * 8;
        float4 o0 = {d0.x*inv, d0.y*inv, d0.z*inv, d0.w*inv};
        float4 o1 = {d1.x*inv, d1.y*inv, d1.z*inv, d1.w*inv};
        *(float4*)(op)     = o0;
        *(float4*)(op + 4) = o1;
    }
}

// ================= legacy fallback path (small ws) =================
__global__ __launch_bounds__(128) void k_sample(
    const float* __restrict__ x,  const float* __restrict__ kp,
    const float* __restrict__ w1, const float* __restrict__ b1,
    const float* __restrict__ w2, const float* __restrict__ b2,
    float* __restrict__ feats)
{
    const int n  = blockIdx.x;
    const int bi = n / NK;
    const int t  = threadIdx.x;

    __shared__ __align__(16) float patch[CH * 9];
    __shared__ float red[16 * 8];
    __shared__ float o1[16];
    __shared__ float offv[16];

    const float kx  = kp[(size_t)n * 2 + 0];
    const float ky  = kp[(size_t)n * 2 + 1];
    const float kwx = (kx * 0.5f + 0.5f) * (float)(WW - 1);
    const float kwy = (ky * 0.5f + 0.5f) * (float)(HH - 1);
    const int kwlx = (int)kwx;
    const int kwly = (int)kwy;
    int cx = (int)((float)kwlx - 0.5f);
    int cy = (int)((float)kwly - 0.5f);
    cx = min(max(cx, 0), WW - 1 - 3);
    cy = min(max(cy, 0), HH - 1 - 3);

    const float* xb = x + ((size_t)bi * CH + t) * HWSZ;
    {
        const float* p0 = xb + cy * WW + cx;
        #pragma unroll
        for (int i = 0; i < 3; ++i) {
            patch[t * 9 + i * 3 + 0] = p0[i * WW + 0];
            patch[t * 9 + i * 3 + 1] = p0[i * WW + 1];
            patch[t * 9 + i * 3 + 2] = p0[i * WW + 2];
        }
    }
    __syncthreads();
    {
        const int o = t & 15, g = t >> 4;
        const float4* wp = (const float4*)(w1 + o * 1152 + g * 144);
        const float4* pp = (const float4*)(patch + g * 144);
        float s = 0.f;
        #pragma unroll
        for (int q = 0; q < 36; ++q) {
            float4 wv = wp[q];
            float4 pv = pp[q];
            s = fmaf(wv.x, pv.x, fmaf(wv.y, pv.y, fmaf(wv.z, pv.z, fmaf(wv.w, pv.w, s))));
        }
        red[o * 8 + g] = s;
    }
    __syncthreads();
    if (t < 16) {
        float s = b1[t];
        #pragma unroll
        for (int g = 0; g < 8; ++g) s += red[t * 8 + g];
        o1[t] = fmaxf(s, 0.f);
    }
    __syncthreads();
    if (t < 16) {
        float s = b2[t];
        #pragma unroll
        for (int j = 0; j < 16; ++j) s = fmaf(o1[j], w2[t * 16 + j], s);
        offv[t] = fminf(fmaxf(s, -80.f), 80.f);
    }
    __syncthreads();

    #pragma unroll
    for (int p = 0; p < NPOS; ++p) {
        const float px = kwx + offv[p];
        const float py = kwy + offv[8 + p];
        const float x0 = floorf(px), y0 = floorf(py);
        const float wx = px - x0, wy = py - y0;
        float acc = 0.f;
        #pragma unroll
        for (int dy = 0; dy < 2; ++dy) {
            const float yc = y0 + (float)dy;
            const bool vy = (yc >= 0.f) && (yc <= (float)(HH - 1));
            const int  yi = (int)fminf(fmaxf(yc, 0.f), (float)(HH - 1));
            const float wyv = dy ? wy : (1.f - wy);
            #pragma unroll
            for (int dx = 0; dx < 2; ++dx) {
                const float xc = x0 + (float)dx;
                const bool vx = (xc >= 0.f) && (xc <= (float)(WW - 1));
                const int  xi = (int)fminf(fmaxf(xc, 0.f), (float)(WW - 1));
                const float wxv = dx ? wx : (1.f - wx);
                float v = xb[yi * WW + xi];
                v = (vx && vy) ? v : 0.f;
                acc = fmaf(v, wxv * wyv, acc);
            }
        }
        feats[((size_t)n * 8 + p) * CH + t] = acc;
    }
}

__global__ __launch_bounds__(256) void k_sf_legacy(float* __restrict__ gbuf,
                                                   const float* __restrict__ sfT)
{
    const int m0 = blockIdx.x * 64;
    const int t  = threadIdx.x;
    __shared__ __align__(16) float AT[128 * 68];

    #pragma unroll
    for (int i = 0; i < 32; ++i) {
        int flat = i * 256 + t;
        int mm = flat >> 7, kk = flat & 127;
        AT[kk * 68 + mm] = gbuf[(size_t)(m0 + mm) * 128 + kk];
    }
    __syncthreads();

    const int tx = t & 31, ty = t >> 5;
    const int d0 = tx * 4, mb = ty * 8;
    float acc[8][4];
    #pragma unroll
    for (int i = 0; i < 8; ++i)
        #pragma unroll
        for (int j = 0; j < 4; ++j) acc[i][j] = 0.f;

    #pragma unroll 4
    for (int k = 0; k < 128; ++k) {
        float4 a0 = *(const float4*)(AT + k * 68 + mb);
        float4 a1 = *(const float4*)(AT + k * 68 + mb + 4);
        float4 bq = *(const float4*)(sfT + k * 128 + d0);
        float a[8] = {a0.x, a0.y, a0.z, a0.w, a1.x, a1.y, a1.z, a1.w};
        float b4[4] = {bq.x, bq.y, bq.z, bq.w};
        #pragma unroll
        for (int i = 0; i < 8; ++i)
            #pragma unroll
            for (int j = 0; j < 4; ++j)
                acc[i][j] = fmaf(a[i], b4[j], acc[i][j]);
    }

    #pragma unroll
    for (int i = 0; i < 8; ++i) {
        float4 o;
        float* ov = &o.x;
        #pragma unroll
        for (int j = 0; j < 4; ++j) {
            float v = acc[i][j];
            float r = v > 0.f ? v : 1.6732632423543772f * expm1f(v);
            ov[j] = 1.0507009873554805f * r;
        }
        *(float4*)(gbuf + (size_t)(m0 + mb + i) * 128 + d0) = o;
    }
}

__global__ __launch_bounds__(256) void k_agg_mono(const float* __restrict__ gbuf,
                                                  const float* __restrict__ aggw,
                                                  float* __restrict__ out)
{
    const int m0 = blockIdx.x * 64;
    const int t  = threadIdx.x;
    __shared__ __align__(16) float AT[128 * 68];

    const int tx = t & 31, ty = t >> 5;
    const int d0 = tx * 4, mb = ty * 8;
    float acc[8][4];
    #pragma unroll
    for (int i = 0; i < 8; ++i)
        #pragma unroll
        for (int j = 0; j < 4; ++j) acc[i][j] = 0.f;

    for (int kc = 0; kc < 8; ++kc) {
        __syncthreads();
        #pragma unroll
        for (int i = 0; i < 32; ++i) {
            int flat = i * 256 + t;
            int mm = flat >> 7, kk = flat & 127;
            AT[kk * 68 + mm] = gbuf[(size_t)(m0 + mm) * 1024 + kc * 128 + kk];
        }
        __syncthreads();
        #pragma unroll 4
        for (int kk = 0; kk < 128; ++kk) {
            float4 a0 = *(const float4*)(AT + kk * 68 + mb);
            float4 a1 = *(const float4*)(AT + kk * 68 + mb + 4);
            float4 bq = *(const float4*)(aggw + (size_t)(kc * 128 + kk) * 128 + d0);
            float a[8] = {a0.x, a0.y, a0.z, a0.w, a1.x, a1.y, a1.z, a1.w};
            float b4[4] = {bq.x, bq.y, bq.z, bq.w};
            #pragma unroll
            for (int i = 0; i < 8; ++i)
                #pragma unroll
                for (int j = 0; j < 4; ++j)
                    acc[i][j] = fmaf(a[i], b4[j], acc[i][j]);
        }
    }

    #pragma unroll
    for (int i = 0; i < 8; ++i) {
        float s = acc[i][0] * acc[i][0] + acc[i][1] * acc[i][1]
                + acc[i][2] * acc[i][2] + acc[i][3] * acc[i][3];
        #pragma unroll
        for (int m = 16; m; m >>= 1) s += __shfl_xor(s, m);
        const float inv = 1.f / fmaxf(sqrtf(s), 1e-12f);
        float4 o = {acc[i][0] * inv, acc[i][1] * inv, acc[i][2] * inv, acc[i][3] * inv};
        *(float4*)(out + (size_t)(m0 + mb + i) * 128 + d0) = o;
    }
}

extern "C" void kernel_launch(void* const* d_in, const int* in_sizes, int n_in,
                              void* d_out, int out_size, void* d_ws, size_t ws_size,
                              hipStream_t stream)
{
    const float* x   = (const float*)d_in[0];
    const float* kp  = (const float*)d_in[1];
    const float* w1  = (const float*)d_in[2];
    const float* b1  = (const float*)d_in[3];
    const float* w2  = (const float*)d_in[4];
    const float* b2  = (const float*)d_in[5];
    const float* sfw = (const float*)d_in[6];
    const float* agg = (const float*)d_in[7];
    float* out = (float*)d_out;

    if (ws_size < WS_MIN) return;

    char*  ws    = (char*)d_ws;
    float* sfT   = (float*)(ws + OFF_SFT);
    float* w1T   = (float*)(ws + OFF_W1T);
    unsigned short* xclb = (unsigned short*)(ws + OFF_XCL);  // bf16 NHWC x
    unsigned short* sfB  = (unsigned short*)(ws + OFF_SFB);
    unsigned short* agB  = (unsigned short*)(ws + OFF_AGB);

    k_prep<<<712, 256, 0, stream>>>(sfw, w1, agg, sfT, w1T, sfB, agB);

    if (ws_size >= WS_FULL) {
        dim3 grid(HWSZ / 64, BB);
        k_tr  <<<grid, 256, 0, stream>>>(x, xclb);
        k_mega<<<NKP / 16, 256, 0, stream>>>(xclb, kp, w1T, b1, w2, b2, sfB, agB, out);
    } else {
        float* feats = (float*)ws;
        k_sample   <<<NKP, 128, 0, stream>>>(x, kp, w1, b1, w2, b2, feats);
        k_sf_legacy<<<2000, 256, 0, stream>>>(feats, sfT);
        k_agg_mono <<<250,  256, 0, stream>>>(feats, agg, out);
    }
}

// Round 9
// 301.300 us; speedup vs baseline: 1.0697x; 1.0697x over previous
//
#include <hip/hip_runtime.h>
#include <cstdint>
#include <cmath>

#define BB   4
#define NK   4000
#define NKP  (BB*NK)      // 16000 keypoints total
#define CH   128
#define HH   240
#define WW   320
#define HWSZ (HH*WW)
#define NPOS 8

typedef __attribute__((ext_vector_type(8))) short short8;
typedef __attribute__((ext_vector_type(8))) unsigned short ushort8;
typedef __attribute__((ext_vector_type(4))) float f32x4;

// ws layout (bytes):
//   sfT      : 65,536  @ 65,536,000  [legacy]
//   w1T      : 73,728  @ 65,601,536
//   xclb     : bf16 NHWC x, 78,643,200 @ 65,675,264
//   sfB      : 32,768  @ 222,961,664  [bf16 MFMA-packed sf_w^T]
//   agB      : 262,144 @ 222,994,432  [bf16 MFMA-packed agg_w]
static constexpr size_t OFF_POS  = 32768000;
static constexpr size_t OFF_SFT  = 65536000;
static constexpr size_t OFF_W1T  = 65601536;
static constexpr size_t OFF_XCL  = 65675264;
static constexpr size_t OFF_SFB  = 222961664;
static constexpr size_t OFF_AGB  = 222994432;
static constexpr size_t WS_FULL  = 223256576;
static constexpr size_t WS_MIN   = 65675264;

__device__ __forceinline__ unsigned short f2bf(float f) {   // RNE
    unsigned int u = __float_as_uint(f);
    u += 0x7fff + ((u >> 16) & 1);
    return (unsigned short)(u >> 16);
}
__device__ __forceinline__ float bf2f(unsigned short u) {
    return __uint_as_float((unsigned)u << 16);
}

// ---------------- K0: weight prep ----------------
__global__ __launch_bounds__(256) void k_prep(const float* __restrict__ sfw,
                                              const float* __restrict__ w1,
                                              const float* __restrict__ aggw,
                                              float* __restrict__ sfT,
                                              float* __restrict__ w1T,
                                              unsigned short* __restrict__ sfB,
                                              unsigned short* __restrict__ agB)
{
    int id = blockIdx.x * 256 + threadIdx.x;   // 182272 total
    if (id < 16384) {
        int cc = id >> 7, dd = id & 127;
        sfT[cc * 128 + dd] = sfw[dd * 128 + cc];
    } else if (id < 16384 + 18432) {
        int j = id - 16384;
        int o = j / 1152, r = j % 1152;
        int k = r >> 7, c = r & 127;
        w1T[j] = w1[o * 1152 + c * 9 + k];
    } else if (id < 16384 + 18432 + 16384) {
        int idx = id - (16384 + 18432);
        int j = idx & 7, lane = (idx >> 3) & 63, nt = (idx >> 9) & 7, kc32 = (idx >> 12) & 3;
        int k = kc32 * 32 + (lane >> 4) * 8 + j;
        int n = nt * 16 + (lane & 15);
        sfB[idx] = f2bf(sfw[n * 128 + k]);     // B[c][d] = sf_w[d][c]
    } else if (id < 16384 + 18432 + 16384 + 131072) {
        int idx = id - (16384 + 18432 + 16384);
        int local = idx & 16383, kc = idx >> 14;
        int j = local & 7, lane = (local >> 3) & 63, nt = (local >> 9) & 7, kc32 = (local >> 12) & 3;
        int k = kc * 128 + kc32 * 32 + (lane >> 4) * 8 + j;
        int n = nt * 16 + (lane & 15);
        agB[idx] = f2bf(aggw[(size_t)k * 128 + n]);
    }
}

// ---------------- K0b: NCHW fp32 -> NHWC bf16, 128ch x 64px tile ----------------
// k_tr is closed: 4 structural theories falsified (coalescing width, occupancy,
// rd/wr overlap, XCD remap); only byte-halving (bf16) moved it. ~62 us floor.
__global__ __launch_bounds__(256) void k_tr(const float* __restrict__ x,
                                            unsigned short* __restrict__ xclb)
{
    const int b  = blockIdx.y;
    const int p0 = blockIdx.x * 64;
    const int t  = threadIdx.x;
    __shared__ float tile[64 * 129];

    #pragma unroll
    for (int i = 0; i < 8; ++i) {
        int flat = i * 256 + t;          // 0..2047
        int c  = flat >> 4;              // 0..127
        int p4 = flat & 15;              // 0..15
        float4 v = *(const float4*)(x + ((size_t)(b * 128 + c)) * HWSZ + p0 + p4 * 4);
        tile[(p4 * 4 + 0) * 129 + c] = v.x;
        tile[(p4 * 4 + 1) * 129 + c] = v.y;
        tile[(p4 * 4 + 2) * 129 + c] = v.z;
        tile[(p4 * 4 + 3) * 129 + c] = v.w;
    }
    __syncthreads();
    #pragma unroll
    for (int j = 0; j < 4; ++j) {
        int flat = j * 256 + t;          // 0..1023
        int p  = flat >> 4;              // 0..63
        int c8 = flat & 15;              // 0..15
        ushort8 o;
        #pragma unroll
        for (int k = 0; k < 8; ++k)
            o[k] = f2bf(tile[p * 129 + c8 * 8 + k]);
        *(ushort8*)(xclb + ((size_t)b * HWSZ + p0 + p) * CH + c8 * 8) = o;
    }
}

// ---------------- K1: mega-fused keypoint pipeline (4 blocks/CU) ----------------
// 16 kp / block, grid 1000. LDS cut 52.0->39.7 KB so all 1000 blocks are
// co-resident at 4 blocks/CU (was 3/CU -> two dispatch rounds, 2nd 70% idle):
//   - pl staged as bf16 (LOSSLESS: values come from bf16 xclb), stride 392 (+8
//     pad -> conv read 2-way banks = free)
//   - As eliminated: each lane gathers its own MFMA A-fragment (row w*16+fr,
//     channels q*32+fq*8) directly; same corner fma order -> bit-identical
//   - Dl aliases GlB; extra barrier between last Gl read and Dl write
__global__ __launch_bounds__(256, 4) void k_mega(
    const unsigned short* __restrict__ xclb, const float* __restrict__ kp,
    const float* __restrict__ w1T, const float* __restrict__ b1,
    const float* __restrict__ w2,  const float* __restrict__ b2,
    const unsigned short* __restrict__ sfB,
    const unsigned short* __restrict__ agB,
    float* __restrict__ out)
{
    const int t  = threadIdx.x;
    const int n0 = blockIdx.x * 16;
    const int bi = n0 / NK;              // uniform per block (NK % 16 == 0)

    __shared__ __align__(16) char U[37376];
    float* wl = (float*)U;                               // [16*388] f32  24832 B (A)
    unsigned short* plb = (unsigned short*)(U + 24832);  // [16*392] bf16 12544 B (A)
    char*  GlB = U;                                      // [128 x 256B]  32768 B (B,C)
    float* Dl = (float*)U;                               // [16*132] f32   8448 B (C, after barrier)
    __shared__ float  o1l[16 * 16];
    __shared__ float  kwl[16 * 2];
    __shared__ int2   cxyl[16];
    __shared__ float2 posl[128];

    // ================= phase A: offset conv + MLP =================
    if (t < 16) {
        const int n = n0 + t;
        float kx = kp[2 * n], ky = kp[2 * n + 1];
        float kwx = (kx * 0.5f + 0.5f) * (float)(WW - 1);
        float kwy = (ky * 0.5f + 0.5f) * (float)(HH - 1);
        kwl[t * 2 + 0] = kwx;
        kwl[t * 2 + 1] = kwy;
        int cx = (int)((float)((int)kwx) - 0.5f);
        int cy = (int)((float)((int)kwy) - 0.5f);
        cx = min(max(cx, 0), WW - 4);
        cy = min(max(cy, 0), HH - 4);
        cxyl[t] = make_int2(cx, cy);
    }
    __syncthreads();

    const int o_c  = t >> 4;
    const int kp_c = t & 15;
    float acc0 = 0.f, acc1 = 0.f;
    const unsigned short* xb = xclb + (size_t)bi * HWSZ * CH;

    for (int h = 0; h < 3; ++h) {
        if (h) __syncthreads();
        #pragma unroll
        for (int i = 0; i < 6; ++i) {
            int idx = i * 256 + t;
            int o = idx / 96, c4 = idx % 96;
            *(float4*)&wl[o * 388 + c4 * 4] =
                *(const float4*)&w1T[o * 1152 + h * 384 + c4 * 4];
        }
        #pragma unroll
        for (int i = 0; i < 3; ++i) {
            int idx = i * 256 + t;       // 0..767
            int kk = idx / 48, r = idx % 48;
            int px = r >> 4, c8 = r & 15;
            int2 c = cxyl[kk];
            ushort8 raw = *(const ushort8*)(xb + ((size_t)(c.y + h) * WW + (c.x + px)) * CH + c8 * 8);
            *(ushort8*)&plb[kk * 392 + px * 128 + c8 * 8] = raw;   // raw bf16, no cvt
        }
        __syncthreads();
        #pragma unroll 4
        for (int g = 0; g < 48; ++g) {
            float4 w0  = *(const float4*)&wl[o_c * 388 + g * 8];
            float4 w1v = *(const float4*)&wl[o_c * 388 + g * 8 + 4];
            ushort8 p8 = *(const ushort8*)&plb[kp_c * 392 + g * 8];
            // same fma nesting as fp32 version (w first, innermost .w)
            acc0 = fmaf(w0.x, bf2f(p8[0]), fmaf(w0.y, bf2f(p8[1]),
                   fmaf(w0.z, bf2f(p8[2]), fmaf(w0.w, bf2f(p8[3]), acc0))));
            acc1 = fmaf(w1v.x, bf2f(p8[4]), fmaf(w1v.y, bf2f(p8[5]),
                   fmaf(w1v.z, bf2f(p8[6]), fmaf(w1v.w, bf2f(p8[7]), acc1))));
        }
    }

    __syncthreads();
    o1l[kp_c * 16 + o_c] = fmaxf(acc0 + acc1 + b1[o_c], 0.f);
    __syncthreads();

    if (t < 128) {
        const int kk = t >> 3, j = t & 7;
        float sx = b2[j], sy = b2[8 + j];
        #pragma unroll
        for (int i = 0; i < 16; ++i) {
            float v = o1l[kk * 16 + i];
            sx = fmaf(v, w2[j * 16 + i], sx);
            sy = fmaf(v, w2[(8 + j) * 16 + i], sy);
        }
        sx = fminf(fmaxf(sx, -80.f), 80.f);
        sy = fminf(fmaxf(sy, -80.f), 80.f);
        posl[kk * 8 + j] = make_float2(kwl[kk * 2 + 0] + sx, kwl[kk * 2 + 1] + sy);
    }
    __syncthreads();

    // ====== phase B: direct-fragment gather + sf MFMA + selu -> Gl (no As) ======
    const int w = t >> 6, l = t & 63;
    const int fr = l & 15, fq = l >> 4;

    for (int chunk = 0; chunk < 2; ++chunk) {
        const int arow = chunk * 64 + w * 16 + fr;   // sample row this lane owns
        float2 P = posl[arow];
        const float x0 = floorf(P.x), y0 = floorf(P.y);
        const float wx = P.x - x0, wy = P.y - y0;
        const unsigned short* cp[4];
        float cw[4];
        #pragma unroll
        for (int dy = 0; dy < 2; ++dy) {
            const float yc = y0 + (float)dy;
            const bool vy = (yc >= 0.f) && (yc <= (float)(HH - 1));
            const int  yi = (int)fminf(fmaxf(yc, 0.f), (float)(HH - 1));
            const float wyv = dy ? wy : (1.f - wy);
            #pragma unroll
            for (int dx = 0; dx < 2; ++dx) {
                const float xc = x0 + (float)dx;
                const bool vx = (xc >= 0.f) && (xc <= (float)(WW - 1));
                const int  xi = (int)fminf(fmaxf(xc, 0.f), (float)(WW - 1));
                cp[dy * 2 + dx] = xb + ((size_t)yi * WW + xi) * CH;
                cw[dy * 2 + dx] = (vx && vy) ? (dx ? wx : (1.f - wx)) * wyv : 0.f;
            }
        }

        short8 a[4];
        #pragma unroll
        for (int q = 0; q < 4; ++q) {
            const int ch = q * 32 + fq * 8;
            ushort8 c0 = *(const ushort8*)(cp[0] + ch);
            ushort8 c1 = *(const ushort8*)(cp[1] + ch);
            ushort8 c2 = *(const ushort8*)(cp[2] + ch);
            ushort8 c3 = *(const ushort8*)(cp[3] + ch);
            short8 av;
            #pragma unroll
            for (int j = 0; j < 8; ++j) {
                float s = fmaf(bf2f(c0[j]), cw[0], 0.f);   // same corner order
                s = fmaf(bf2f(c1[j]), cw[1], s);
                s = fmaf(bf2f(c2[j]), cw[2], s);
                s = fmaf(bf2f(c3[j]), cw[3], s);
                av[j] = (short)f2bf(s);
            }
            a[q] = av;
        }

        f32x4 acc[8];
        #pragma unroll
        for (int nt = 0; nt < 8; ++nt)
            #pragma unroll
            for (int r = 0; r < 4; ++r) acc[nt][r] = 0.f;

        #pragma unroll 2
        for (int nt = 0; nt < 8; ++nt) {
            short8 b[4];
            #pragma unroll
            for (int q = 0; q < 4; ++q)
                b[q] = *(const short8*)(sfB + ((size_t)(q * 8 + nt) * 64 + l) * 8);
            #pragma unroll
            for (int q = 0; q < 4; ++q)
                acc[nt] = __builtin_amdgcn_mfma_f32_16x16x32_bf16(a[q], b[q], acc[nt], 0, 0, 0);
        }

        #pragma unroll
        for (int nt = 0; nt < 8; ++nt)
            #pragma unroll
            for (int r = 0; r < 4; ++r) {
                float v = acc[nt][r];
                // selu; __expf ok: result rounded to bf16 (quantum ~4e-3 rel).
                float e = v > 0.f ? v : 1.6732632423543772f * (__expf(v) - 1.f);
                const int row = chunk * 64 + w * 16 + fq * 4 + r;
                unsigned byte = (unsigned)(row * 256 + (nt * 16 + fr) * 2);
                byte ^= ((unsigned)((row >> 3) & 7)) << 4;
                *(unsigned short*)(GlB + byte) = f2bf(1.0507009873554805f * e);
            }
    }
    __syncthreads();

    // ================= phase C: agg MFMA + normalize =================
    f32x4 acc2[2];
    #pragma unroll
    for (int i = 0; i < 2; ++i)
        #pragma unroll
        for (int r = 0; r < 4; ++r) acc2[i][r] = 0.f;

    const int nt0 = w * 2;
    #pragma unroll 4
    for (int kk = 0; kk < 32; ++kk) {
        const int row = fr * 8 + (kk >> 2);            // n_local*8 + p
        unsigned byte = (unsigned)(row * 256 + ((kk & 3) * 32 + fq * 8) * 2);
        byte ^= ((unsigned)((row >> 3) & 7)) << 4;
        short8 a2 = *(const short8*)(GlB + byte);
        #pragma unroll
        for (int i = 0; i < 2; ++i) {
            short8 b2 = *(const short8*)(agB + (size_t)(kk >> 2) * 16384 +
                ((size_t)(((kk & 3) * 8 + nt0 + i) * 64 + l)) * 8);
            acc2[i] = __builtin_amdgcn_mfma_f32_16x16x32_bf16(a2, b2, acc2[i], 0, 0, 0);
        }
    }

    __syncthreads();                 // all GlB reads done before Dl (aliases GlB)
    #pragma unroll
    for (int i = 0; i < 2; ++i)
        #pragma unroll
        for (int r = 0; r < 4; ++r)
            Dl[(fq * 4 + r) * 132 + w * 32 + i * 16 + fr] = acc2[i][r];
    __syncthreads();

    {
        const int row = t >> 4, seg = t & 15;
        const float* dr = Dl + row * 132 + seg * 8;
        float4 d0 = *(const float4*)(dr);
        float4 d1 = *(const float4*)(dr + 4);
        float s = d0.x*d0.x + d0.y*d0.y + d0.z*d0.z + d0.w*d0.w
                + d1.x*d1.x + d1.y*d1.y + d1.z*d1.z + d1.w*d1.w;
        #pragma unroll
        for (int m = 1; m < 16; m <<= 1) s += __shfl_xor(s, m);
        const float inv = 1.f / fmaxf(sqrtf(s), 1e-12f);
        float* op = out + (size_t)(n0 + row) * 128 + seg * 8;
        float4 o0 = {d0.x*inv, d0.y*inv, d0.z*inv, d0.w*inv};
        float4 o1 = {d1.x*inv, d1.y*inv, d1.z*inv, d1.w*inv};
        *(float4*)(op)     = o0;
        *(float4*)(op + 4) = o1;
    }
}

// ================= legacy fallback path (small ws) =================
__global__ __launch_bounds__(128) void k_sample(
    const float* __restrict__ x,  const float* __restrict__ kp,
    const float* __restrict__ w1, const float* __restrict__ b1,
    const float* __restrict__ w2, const float* __restrict__ b2,
    float* __restrict__ feats)
{
    const int n  = blockIdx.x;
    const int bi = n / NK;
    const int t  = threadIdx.x;

    __shared__ __align__(16) float patch[CH * 9];
    __shared__ float red[16 * 8];
    __shared__ float o1[16];
    __shared__ float offv[16];

    const float kx  = kp[(size_t)n * 2 + 0];
    const float ky  = kp[(size_t)n * 2 + 1];
    const float kwx = (kx * 0.5f + 0.5f) * (float)(WW - 1);
    const float kwy = (ky * 0.5f + 0.5f) * (float)(HH - 1);
    const int kwlx = (int)kwx;
    const int kwly = (int)kwy;
    int cx = (int)((float)kwlx - 0.5f);
    int cy = (int)((float)kwly - 0.5f);
    cx = min(max(cx, 0), WW - 1 - 3);
    cy = min(max(cy, 0), HH - 1 - 3);

    const float* xb = x + ((size_t)bi * CH + t) * HWSZ;
    {
        const float* p0 = xb + cy * WW + cx;
        #pragma unroll
        for (int i = 0; i < 3; ++i) {
            patch[t * 9 + i * 3 + 0] = p0[i * WW + 0];
            patch[t * 9 + i * 3 + 1] = p0[i * WW + 1];
            patch[t * 9 + i * 3 + 2] = p0[i * WW + 2];
        }
    }
    __syncthreads();
    {
        const int o = t & 15, g = t >> 4;
        const float4* wp = (const float4*)(w1 + o * 1152 + g * 144);
        const float4* pp = (const float4*)(patch + g * 144);
        float s = 0.f;
        #pragma unroll
        for (int q = 0; q < 36; ++q) {
            float4 wv = wp[q];
            float4 pv = pp[q];
            s = fmaf(wv.x, pv.x, fmaf(wv.y, pv.y, fmaf(wv.z, pv.z, fmaf(wv.w, pv.w, s))));
        }
        red[o * 8 + g] = s;
    }
    __syncthreads();
    if (t < 16) {
        float s = b1[t];
        #pragma unroll
        for (int g = 0; g < 8; ++g) s += red[t * 8 + g];
        o1[t] = fmaxf(s, 0.f);
    }
    __syncthreads();
    if (t < 16) {
        float s = b2[t];
        #pragma unroll
        for (int j = 0; j < 16; ++j) s = fmaf(o1[j], w2[t * 16 + j], s);
        offv[t] = fminf(fmaxf(s, -80.f), 80.f);
    }
    __syncthreads();

    #pragma unroll
    for (int p = 0; p < NPOS; ++p) {
        const float px = kwx + offv[p];
        const float py = kwy + offv[8 + p];
        const float x0 = floorf(px), y0 = floorf(py);
        const float wx = px - x0, wy = py - y0;
        float acc = 0.f;
        #pragma unroll
        for (int dy = 0; dy < 2; ++dy) {
            const float yc = y0 + (float)dy;
            const bool vy = (yc >= 0.f) && (yc <= (float)(HH - 1));
            const int  yi = (int)fminf(fmaxf(yc, 0.f), (float)(HH - 1));
            const float wyv = dy ? wy : (1.f - wy);
            #pragma unroll
            for (int dx = 0; dx < 2; ++dx) {
                const float xc = x0 + (float)dx;
                const bool vx = (xc >= 0.f) && (xc <= (float)(WW - 1));
                const int  xi = (int)fminf(fmaxf(xc, 0.f), (float)(WW - 1));
                const float wxv = dx ? wx : (1.f - wx);
                float v = xb[yi * WW + xi];
                v = (vx && vy) ? v : 0.f;
                acc = fmaf(v, wxv * wyv, acc);
            }
        }
        feats[((size_t)n * 8 + p) * CH + t] = acc;
    }
}

__global__ __launch_bounds__(256) void k_sf_legacy(float* __restrict__ gbuf,
                                                   const float* __restrict__ sfT)
{
    const int m0 = blockIdx.x * 64;
    const int t  = threadIdx.x;
    __shared__ __align__(16) float AT[128 * 68];

    #pragma unroll
    for (int i = 0; i < 32; ++i) {
        int flat = i * 256 + t;
        int mm = flat >> 7, kk = flat & 127;
        AT[kk * 68 + mm] = gbuf[(size_t)(m0 + mm) * 128 + kk];
    }
    __syncthreads();

    const int tx = t & 31, ty = t >> 5;
    const int d0 = tx * 4, mb = ty * 8;
    float acc[8][4];
    #pragma unroll
    for (int i = 0; i < 8; ++i)
        #pragma unroll
        for (int j = 0; j < 4; ++j) acc[i][j] = 0.f;

    #pragma unroll 4
    for (int k = 0; k < 128; ++k) {
        float4 a0 = *(const float4*)(AT + k * 68 + mb);
        float4 a1 = *(const float4*)(AT + k * 68 + mb + 4);
        float4 bq = *(const float4*)(sfT + k * 128 + d0);
        float a[8] = {a0.x, a0.y, a0.z, a0.w, a1.x, a1.y, a1.z, a1.w};
        float b4[4] = {bq.x, bq.y, bq.z, bq.w};
        #pragma unroll
        for (int i = 0; i < 8; ++i)
            #pragma unroll
            for (int j = 0; j < 4; ++j)
                acc[i][j] = fmaf(a[i], b4[j], acc[i][j]);
    }

    #pragma unroll
    for (int i = 0; i < 8; ++i) {
        float4 o;
        float* ov = &o.x;
        #pragma unroll
        for (int j = 0; j < 4; ++j) {
            float v = acc[i][j];
            float r = v > 0.f ? v : 1.6732632423543772f * expm1f(v);
            ov[j] = 1.0507009873554805f * r;
        }
        *(float4*)(gbuf + (size_t)(m0 + mb + i) * 128 + d0) = o;
    }
}

__global__ __launch_bounds__(256) void k_agg_mono(const float* __restrict__ gbuf,
                                                  const float* __restrict__ aggw,
                                                  float* __restrict__ out)
{
    const int m0 = blockIdx.x * 64;
    const int t  = threadIdx.x;
    __shared__ __align__(16) float AT[128 * 68];

    const int tx = t & 31, ty = t >> 5;
    const int d0 = tx * 4, mb = ty * 8;
    float acc[8][4];
    #pragma unroll
    for (int i = 0; i < 8; ++i)
        #pragma unroll
        for (int j = 0; j < 4; ++j) acc[i][j] = 0.f;

    for (int kc = 0; kc < 8; ++kc) {
        __syncthreads();
        #pragma unroll
        for (int i = 0; i < 32; ++i) {
            int flat = i * 256 + t;
            int mm = flat >> 7, kk = flat & 127;
            AT[kk * 68 + mm] = gbuf[(size_t)(m0 + mm) * 1024 + kc * 128 + kk];
        }
        __syncthreads();
        #pragma unroll 4
        for (int kk = 0; kk < 128; ++kk) {
            float4 a0 = *(const float4*)(AT + kk * 68 + mb);
            float4 a1 = *(const float4*)(AT + kk * 68 + mb + 4);
            float4 bq = *(const float4*)(aggw + (size_t)(kc * 128 + kk) * 128 + d0);
            float a[8] = {a0.x, a0.y, a0.z, a0.w, a1.x, a1.y, a1.z, a1.w};
            float b4[4] = {bq.x, bq.y, bq.z, bq.w};
            #pragma unroll
            for (int i = 0; i < 8; ++i)
                #pragma unroll
                for (int j = 0; j < 4; ++j)
                    acc[i][j] = fmaf(a[i], b4[j], acc[i][j]);
        }
    }

    #pragma unroll
    for (int i = 0; i < 8; ++i) {
        float s = acc[i][0] * acc[i][0] + acc[i][1] * acc[i][1]
                + acc[i][2] * acc[i][2] + acc[i][3] * acc[i][3];
        #pragma unroll
        for (int m = 16; m; m >>= 1) s += __shfl_xor(s, m);
        const float inv = 1.f / fmaxf(sqrtf(s), 1e-12f);
        float4 o = {acc[i][0] * inv, acc[i][1] * inv, acc[i][2] * inv, acc[i][3] * inv};
        *(float4*)(out + (size_t)(m0 + mb + i) * 128 + d0) = o;
    }
}

extern "C" void kernel_launch(void* const* d_in, const int* in_sizes, int n_in,
                              void* d_out, int out_size, void* d_ws, size_t ws_size,
                              hipStream_t stream)
{
    const float* x   = (const float*)d_in[0];
    const float* kp  = (const float*)d_in[1];
    const float* w1  = (const float*)d_in[2];
    const float* b1  = (const float*)d_in[3];
    const float* w2  = (const float*)d_in[4];
    const float* b2  = (const float*)d_in[5];
    const float* sfw = (const float*)d_in[6];
    const float* agg = (const float*)d_in[7];
    float* out = (float*)d_out;

    if (ws_size < WS_MIN) return;

    char*  ws    = (char*)d_ws;
    float* sfT   = (float*)(ws + OFF_SFT);
    float* w1T   = (float*)(ws + OFF_W1T);
    unsigned short* xclb = (unsigned short*)(ws + OFF_XCL);  // bf16 NHWC x
    unsigned short* sfB  = (unsigned short*)(ws + OFF_SFB);
    unsigned short* agB  = (unsigned short*)(ws + OFF_AGB);

    k_prep<<<712, 256, 0, stream>>>(sfw, w1, agg, sfT, w1T, sfB, agB);

    if (ws_size >= WS_FULL) {
        dim3 grid(HWSZ / 64, BB);
        k_tr  <<<grid, 256, 0, stream>>>(x, xclb);
        k_mega<<<NKP / 16, 256, 0, stream>>>(xclb, kp, w1T, b1, w2, b2, sfB, agB, out);
    } else {
        float* feats = (float*)ws;
        k_sample   <<<NKP, 128, 0, stream>>>(x, kp, w1, b1, w2, b2, feats);
        k_sf_legacy<<<2000, 256, 0, stream>>>(feats, sfT);
        k_agg_mono <<<250,  256, 0, stream>>>(feats, agg, out);
    }
}

// Round 10
// 290.851 us; speedup vs baseline: 1.1081x; 1.0359x over previous
//
#include <hip/hip_runtime.h>
#include <cstdint>
#include <cmath>

#define BB   4
#define NK   4000
#define NKP  (BB*NK)      // 16000 keypoints total
#define CH   128
#define HH   240
#define WW   320
#define HWSZ (HH*WW)
#define NPOS 8

typedef __attribute__((ext_vector_type(8))) short short8;
typedef __attribute__((ext_vector_type(8))) unsigned short ushort8;
typedef __attribute__((ext_vector_type(4))) float f32x4;

// ws layout (bytes):
//   sfT      : 65,536  @ 65,536,000  [legacy]
//   w1B      : 36,864  @ 65,601,536  [bf16 MFMA-packed conv weights; reuses w1T slot]
//   xclb     : bf16 NHWC x, 78,643,200 @ 65,675,264
//   sfB      : 32,768  @ 222,961,664  [bf16 MFMA-packed sf_w^T]
//   agB      : 262,144 @ 222,994,432  [bf16 MFMA-packed agg_w]
static constexpr size_t OFF_POS  = 32768000;
static constexpr size_t OFF_SFT  = 65536000;
static constexpr size_t OFF_W1T  = 65601536;
static constexpr size_t OFF_XCL  = 65675264;
static constexpr size_t OFF_SFB  = 222961664;
static constexpr size_t OFF_AGB  = 222994432;
static constexpr size_t WS_FULL  = 223256576;
static constexpr size_t WS_MIN   = 65675264;

__device__ __forceinline__ unsigned short f2bf(float f) {   // RNE
    unsigned int u = __float_as_uint(f);
    u += 0x7fff + ((u >> 16) & 1);
    return (unsigned short)(u >> 16);
}
__device__ __forceinline__ float bf2f(unsigned short u) {
    return __uint_as_float((unsigned)u << 16);
}

// ---------------- K0: merged NCHW->NHWC transpose + weight prep ----------------
// blocks [0,4800): transpose (closed at ~62us: 4 structural theories falsified;
// only byte-halving moved it). blocks [4800,5448): pack sfB/agB/w1B.
__global__ __launch_bounds__(256) void k_trprep(
    const float* __restrict__ x,   unsigned short* __restrict__ xclb,
    const float* __restrict__ sfw, const float* __restrict__ w1,
    const float* __restrict__ aggw,
    unsigned short* __restrict__ sfB, unsigned short* __restrict__ agB,
    unsigned short* __restrict__ w1B)
{
    const int t = threadIdx.x;
    __shared__ float tile[64 * 129];

    if (blockIdx.x < 4800) {
        const int b  = blockIdx.x / 1200;
        const int p0 = (blockIdx.x % 1200) * 64;
        #pragma unroll
        for (int i = 0; i < 8; ++i) {
            int flat = i * 256 + t;          // 0..2047
            int c  = flat >> 4;              // 0..127
            int p4 = flat & 15;              // 0..15
            float4 v = *(const float4*)(x + ((size_t)(b * 128 + c)) * HWSZ + p0 + p4 * 4);
            tile[(p4 * 4 + 0) * 129 + c] = v.x;
            tile[(p4 * 4 + 1) * 129 + c] = v.y;
            tile[(p4 * 4 + 2) * 129 + c] = v.z;
            tile[(p4 * 4 + 3) * 129 + c] = v.w;
        }
        __syncthreads();
        #pragma unroll
        for (int j = 0; j < 4; ++j) {
            int flat = j * 256 + t;          // 0..1023
            int p  = flat >> 4;              // 0..63
            int c8 = flat & 15;              // 0..15
            ushort8 o;
            #pragma unroll
            for (int k = 0; k < 8; ++k)
                o[k] = f2bf(tile[p * 129 + c8 * 8 + k]);
            *(ushort8*)(xclb + ((size_t)b * HWSZ + p0 + p) * CH + c8 * 8) = o;
        }
    } else {
        int id = (blockIdx.x - 4800) * 256 + t;   // 0..165887
        if (id < 16384) {
            int idx = id;
            int j = idx & 7, lane = (idx >> 3) & 63, nt = (idx >> 9) & 7, kc32 = (idx >> 12) & 3;
            int k = kc32 * 32 + (lane >> 4) * 8 + j;
            int n = nt * 16 + (lane & 15);
            sfB[idx] = f2bf(sfw[n * 128 + k]);     // B[c][d] = sf_w[d][c]
        } else if (id < 16384 + 131072) {
            int idx = id - 16384;
            int local = idx & 16383, kc = idx >> 14;
            int j = local & 7, lane = (local >> 3) & 63, nt = (local >> 9) & 7, kc32 = (local >> 12) & 3;
            int k = kc * 128 + kc32 * 32 + (lane >> 4) * 8 + j;
            int n = nt * 16 + (lane & 15);
            agB[idx] = f2bf(aggw[(size_t)k * 128 + n]);
        } else if (id < 16384 + 131072 + 18432) {
            // w1B: B-frag layout (same convention as sfB): elem e -> lane l,
            // k = q*32 + (l>>4)*8 + j over K=1152 (order h,px,c), col o = l&15
            int e = id - (16384 + 131072);
            int j = e & 7, l = (e >> 3) & 63, q = e >> 9;      // q: 0..35
            int k = q * 32 + ((l >> 4) & 3) * 8 + j;           // 0..1151
            int o = l & 15;
            int h = k / 384, rem = k % 384;
            int px = rem >> 7, c = rem & 127;
            w1B[e] = f2bf(w1[o * 1152 + c * 9 + (h * 3 + px)]);
        }
    }
}

// ---------------- K1: mega-fused keypoint pipeline (4 blocks/CU) ----------------
// 16 kp / block, grid 1000, all co-resident (r9 win: single residency round).
//   A: stage full 3x3 patches bf16 (one shot, 9 loads in flight) ->
//      conv as 36x mfma 16x16x32 ([16kp x 1152] @ w1B) -> relu -> MLP -> posl
//      (replaces ~3.5K scalar VALU/thread; only new rounding = w1 -> bf16)
//   B: direct-fragment bilinear gather -> sf MFMA -> selu -> Gl (swizzled)
//   C: agg MFMA (K=1024) -> L2 normalize -> out
// LDS 39,424 B <= 40,960 (160KiB/4).
__global__ __launch_bounds__(256, 4) void k_mega(
    const unsigned short* __restrict__ xclb, const float* __restrict__ kp,
    const unsigned short* __restrict__ w1B, const float* __restrict__ b1,
    const float* __restrict__ w2,  const float* __restrict__ b2,
    const unsigned short* __restrict__ sfB,
    const unsigned short* __restrict__ agB,
    float* __restrict__ out)
{
    const int t  = threadIdx.x;
    const int n0 = blockIdx.x * 16;
    const int bi = n0 / NK;              // uniform per block (NK % 16 == 0)
    const int w  = t >> 6, l = t & 63;
    const int fr = l & 15, fq = l >> 4;

    __shared__ __align__(16) char U[37120];
    unsigned short* plb = (unsigned short*)U;    // [16][1160] bf16 37120 B (A)
    char*  GlB = U;                              // [128 x 256B]  32768 B (B,C)
    float* Dl = (float*)U;                       // [16*132] f32   8448 B (C)
    __shared__ float  o1l[16 * 16];
    __shared__ float  kwl[16 * 2];
    __shared__ int2   cxyl[16];
    __shared__ float2 posl[128];

    // ================= phase A: patches -> conv MFMA -> MLP =================
    if (t < 16) {
        const int n = n0 + t;
        float kx = kp[2 * n], ky = kp[2 * n + 1];
        float kwx = (kx * 0.5f + 0.5f) * (float)(WW - 1);
        float kwy = (ky * 0.5f + 0.5f) * (float)(HH - 1);
        kwl[t * 2 + 0] = kwx;
        kwl[t * 2 + 1] = kwy;
        int cx = (int)((float)((int)kwx) - 0.5f);
        int cy = (int)((float)((int)kwy) - 0.5f);
        cx = min(max(cx, 0), WW - 4);
        cy = min(max(cy, 0), HH - 4);
        cxyl[t] = make_int2(cx, cy);
    }
    __syncthreads();

    const unsigned short* xb = xclb + (size_t)bi * HWSZ * CH;

    // stage all 9 patch pixels x 128 ch per kp, K-order (h, px, c), raw bf16
    #pragma unroll
    for (int i = 0; i < 9; ++i) {
        int idx = i * 256 + t;           // 0..2303
        int kk = idx / 144, rr = idx % 144;
        int oe = rr * 8;                 // elem offset 0..1144
        int h = oe / 384, rem = oe % 384;
        int px = rem >> 7, c0 = rem & 127;
        int2 c = cxyl[kk];
        *(ushort8*)&plb[kk * 1160 + oe] =
            *(const ushort8*)(xb + ((size_t)(c.y + h) * WW + (c.x + px)) * CH + c0);
    }
    __syncthreads();

    // conv: out[16kp x 16o] = patches @ w1B, 36 MFMA (redundant per wave)
    {
        f32x4 ca;
        #pragma unroll
        for (int r = 0; r < 4; ++r) ca[r] = 0.f;
        #pragma unroll 4
        for (int q = 0; q < 36; ++q) {
            short8 a = *(const short8*)(plb + fr * 1160 + q * 32 + fq * 8);
            short8 b = *(const short8*)(w1B + (size_t)(q * 64 + l) * 8);
            ca = __builtin_amdgcn_mfma_f32_16x16x32_bf16(a, b, ca, 0, 0, 0);
        }
        if (w == 0) {
            #pragma unroll
            for (int r = 0; r < 4; ++r)
                o1l[(fq * 4 + r) * 16 + fr] = fmaxf(ca[r] + b1[fr], 0.f);
        }
    }
    __syncthreads();

    if (t < 128) {
        const int kk = t >> 3, j = t & 7;
        float sx = b2[j], sy = b2[8 + j];
        #pragma unroll
        for (int i = 0; i < 16; ++i) {
            float v = o1l[kk * 16 + i];
            sx = fmaf(v, w2[j * 16 + i], sx);
            sy = fmaf(v, w2[(8 + j) * 16 + i], sy);
        }
        sx = fminf(fmaxf(sx, -80.f), 80.f);
        sy = fminf(fmaxf(sy, -80.f), 80.f);
        posl[kk * 8 + j] = make_float2(kwl[kk * 2 + 0] + sx, kwl[kk * 2 + 1] + sy);
    }
    __syncthreads();

    // ====== phase B: direct-fragment gather + sf MFMA + selu -> Gl ======
    for (int chunk = 0; chunk < 2; ++chunk) {
        const int arow = chunk * 64 + w * 16 + fr;   // sample row this lane owns
        float2 P = posl[arow];
        const float x0 = floorf(P.x), y0 = floorf(P.y);
        const float wx = P.x - x0, wy = P.y - y0;
        const unsigned short* cp[4];
        float cw[4];
        #pragma unroll
        for (int dy = 0; dy < 2; ++dy) {
            const float yc = y0 + (float)dy;
            const bool vy = (yc >= 0.f) && (yc <= (float)(HH - 1));
            const int  yi = (int)fminf(fmaxf(yc, 0.f), (float)(HH - 1));
            const float wyv = dy ? wy : (1.f - wy);
            #pragma unroll
            for (int dx = 0; dx < 2; ++dx) {
                const float xc = x0 + (float)dx;
                const bool vx = (xc >= 0.f) && (xc <= (float)(WW - 1));
                const int  xi = (int)fminf(fmaxf(xc, 0.f), (float)(WW - 1));
                cp[dy * 2 + dx] = xb + ((size_t)yi * WW + xi) * CH;
                cw[dy * 2 + dx] = (vx && vy) ? (dx ? wx : (1.f - wx)) * wyv : 0.f;
            }
        }

        short8 a[4];
        #pragma unroll
        for (int q = 0; q < 4; ++q) {
            const int ch = q * 32 + fq * 8;
            ushort8 c0 = *(const ushort8*)(cp[0] + ch);
            ushort8 c1 = *(const ushort8*)(cp[1] + ch);
            ushort8 c2 = *(const ushort8*)(cp[2] + ch);
            ushort8 c3 = *(const ushort8*)(cp[3] + ch);
            short8 av;
            #pragma unroll
            for (int j = 0; j < 8; ++j) {
                float s = fmaf(bf2f(c0[j]), cw[0], 0.f);   // same corner order
                s = fmaf(bf2f(c1[j]), cw[1], s);
                s = fmaf(bf2f(c2[j]), cw[2], s);
                s = fmaf(bf2f(c3[j]), cw[3], s);
                av[j] = (short)f2bf(s);
            }
            a[q] = av;
        }

        f32x4 acc[8];
        #pragma unroll
        for (int nt = 0; nt < 8; ++nt)
            #pragma unroll
            for (int r = 0; r < 4; ++r) acc[nt][r] = 0.f;

        #pragma unroll 2
        for (int nt = 0; nt < 8; ++nt) {
            short8 b[4];
            #pragma unroll
            for (int q = 0; q < 4; ++q)
                b[q] = *(const short8*)(sfB + ((size_t)(q * 8 + nt) * 64 + l) * 8);
            #pragma unroll
            for (int q = 0; q < 4; ++q)
                acc[nt] = __builtin_amdgcn_mfma_f32_16x16x32_bf16(a[q], b[q], acc[nt], 0, 0, 0);
        }

        if (chunk == 0) __syncthreads();   // plb fully dead (conv done pre-MLP barriers)
        #pragma unroll
        for (int nt = 0; nt < 8; ++nt)
            #pragma unroll
            for (int r = 0; r < 4; ++r) {
                float v = acc[nt][r];
                // selu; __expf ok: result rounded to bf16 (quantum ~4e-3 rel).
                float e = v > 0.f ? v : 1.6732632423543772f * (__expf(v) - 1.f);
                const int row = chunk * 64 + w * 16 + fq * 4 + r;
                unsigned byte = (unsigned)(row * 256 + (nt * 16 + fr) * 2);
                byte ^= ((unsigned)((row >> 3) & 7)) << 4;
                *(unsigned short*)(GlB + byte) = f2bf(1.0507009873554805f * e);
            }
    }
    __syncthreads();

    // ================= phase C: agg MFMA + normalize =================
    f32x4 acc2[2];
    #pragma unroll
    for (int i = 0; i < 2; ++i)
        #pragma unroll
        for (int r = 0; r < 4; ++r) acc2[i][r] = 0.f;

    const int nt0 = w * 2;
    #pragma unroll 4
    for (int kk = 0; kk < 32; ++kk) {
        const int row = fr * 8 + (kk >> 2);            // n_local*8 + p
        unsigned byte = (unsigned)(row * 256 + ((kk & 3) * 32 + fq * 8) * 2);
        byte ^= ((unsigned)((row >> 3) & 7)) << 4;
        short8 a2 = *(const short8*)(GlB + byte);
        #pragma unroll
        for (int i = 0; i < 2; ++i) {
            short8 b2 = *(const short8*)(agB + (size_t)(kk >> 2) * 16384 +
                ((size_t)(((kk & 3) * 8 + nt0 + i) * 64 + l)) * 8);
            acc2[i] = __builtin_amdgcn_mfma_f32_16x16x32_bf16(a2, b2, acc2[i], 0, 0, 0);
        }
    }

    __syncthreads();                 // all GlB reads done before Dl (aliases GlB)
    #pragma unroll
    for (int i = 0; i < 2; ++i)
        #pragma unroll
        for (int r = 0; r < 4; ++r)
            Dl[(fq * 4 + r) * 132 + w * 32 + i * 16 + fr] = acc2[i][r];
    __syncthreads();

    {
        const int row = t >> 4, seg = t & 15;
        const float* dr = Dl + row * 132 + seg * 8;
        float4 d0 = *(const float4*)(dr);
        float4 d1 = *(const float4*)(dr + 4);
        float s = d0.x*d0.x + d0.y*d0.y + d0.z*d0.z + d0.w*d0.w
                + d1.x*d1.x + d1.y*d1.y + d1.z*d1.z + d1.w*d1.w;
        #pragma unroll
        for (int m = 1; m < 16; m <<= 1) s += __shfl_xor(s, m);
        const float inv = 1.f / fmaxf(sqrtf(s), 1e-12f);
        float* op = out + (size_t)(n0 + row) * 128 + seg * 8;
        float4 o0 = {d0.x*inv, d0.y*inv, d0.z*inv, d0.w*inv};
        float4 o1 = {d1.x*inv, d1.y*inv, d1.z*inv, d1.w*inv};
        *(float4*)(op)     = o0;
        *(float4*)(op + 4) = o1;
    }
}

// ================= legacy fallback path (small ws) =================
__global__ __launch_bounds__(256) void k_prep_legacy(const float* __restrict__ sfw,
                                                     float* __restrict__ sfT)
{
    int id = blockIdx.x * 256 + threadIdx.x;
    if (id < 16384) {
        int cc = id >> 7, dd = id & 127;
        sfT[cc * 128 + dd] = sfw[dd * 128 + cc];
    }
}

__global__ __launch_bounds__(128) void k_sample(
    const float* __restrict__ x,  const float* __restrict__ kp,
    const float* __restrict__ w1, const float* __restrict__ b1,
    const float* __restrict__ w2, const float* __restrict__ b2,
    float* __restrict__ feats)
{
    const int n  = blockIdx.x;
    const int bi = n / NK;
    const int t  = threadIdx.x;

    __shared__ __align__(16) float patch[CH * 9];
    __shared__ float red[16 * 8];
    __shared__ float o1[16];
    __shared__ float offv[16];

    const float kx  = kp[(size_t)n * 2 + 0];
    const float ky  = kp[(size_t)n * 2 + 1];
    const float kwx = (kx * 0.5f + 0.5f) * (float)(WW - 1);
    const float kwy = (ky * 0.5f + 0.5f) * (float)(HH - 1);
    const int kwlx = (int)kwx;
    const int kwly = (int)kwy;
    int cx = (int)((float)kwlx - 0.5f);
    int cy = (int)((float)kwly - 0.5f);
    cx = min(max(cx, 0), WW - 1 - 3);
    cy = min(max(cy, 0), HH - 1 - 3);

    const float* xb = x + ((size_t)bi * CH + t) * HWSZ;
    {
        const float* p0 = xb + cy * WW + cx;
        #pragma unroll
        for (int i = 0; i < 3; ++i) {
            patch[t * 9 + i * 3 + 0] = p0[i * WW + 0];
            patch[t * 9 + i * 3 + 1] = p0[i * WW + 1];
            patch[t * 9 + i * 3 + 2] = p0[i * WW + 2];
        }
    }
    __syncthreads();
    {
        const int o = t & 15, g = t >> 4;
        const float4* wp = (const float4*)(w1 + o * 1152 + g * 144);
        const float4* pp = (const float4*)(patch + g * 144);
        float s = 0.f;
        #pragma unroll
        for (int q = 0; q < 36; ++q) {
            float4 wv = wp[q];
            float4 pv = pp[q];
            s = fmaf(wv.x, pv.x, fmaf(wv.y, pv.y, fmaf(wv.z, pv.z, fmaf(wv.w, pv.w, s))));
        }
        red[o * 8 + g] = s;
    }
    __syncthreads();
    if (t < 16) {
        float s = b1[t];
        #pragma unroll
        for (int g = 0; g < 8; ++g) s += red[t * 8 + g];
        o1[t] = fmaxf(s, 0.f);
    }
    __syncthreads();
    if (t < 16) {
        float s = b2[t];
        #pragma unroll
        for (int j = 0; j < 16; ++j) s = fmaf(o1[j], w2[t * 16 + j], s);
        offv[t] = fminf(fmaxf(s, -80.f), 80.f);
    }
    __syncthreads();

    #pragma unroll
    for (int p = 0; p < NPOS; ++p) {
        const float px = kwx + offv[p];
        const float py = kwy + offv[8 + p];
        const float x0 = floorf(px), y0 = floorf(py);
        const float wx = px - x0, wy = py - y0;
        float acc = 0.f;
        #pragma unroll
        for (int dy = 0; dy < 2; ++dy) {
            const float yc = y0 + (float)dy;
            const bool vy = (yc >= 0.f) && (yc <= (float)(HH - 1));
            const int  yi = (int)fminf(fmaxf(yc, 0.f), (float)(HH - 1));
            const float wyv = dy ? wy : (1.f - wy);
            #pragma unroll
            for (int dx = 0; dx < 2; ++dx) {
                const float xc = x0 + (float)dx;
                const bool vx = (xc >= 0.f) && (xc <= (float)(WW - 1));
                const int  xi = (int)fminf(fmaxf(xc, 0.f), (float)(WW - 1));
                const float wxv = dx ? wx : (1.f - wx);
                float v = xb[yi * WW + xi];
                v = (vx && vy) ? v : 0.f;
                acc = fmaf(v, wxv * wyv, acc);
            }
        }
        feats[((size_t)n * 8 + p) * CH + t] = acc;
    }
}

__global__ __launch_bounds__(256) void k_sf_legacy(float* __restrict__ gbuf,
                                                   const float* __restrict__ sfT)
{
    const int m0 = blockIdx.x * 64;
    const int t  = threadIdx.x;
    __shared__ __align__(16) float AT[128 * 68];

    #pragma unroll
    for (int i = 0; i < 32; ++i) {
        int flat = i * 256 + t;
        int mm = flat >> 7, kk = flat & 127;
        AT[kk * 68 + mm] = gbuf[(size_t)(m0 + mm) * 128 + kk];
    }
    __syncthreads();

    const int tx = t & 31, ty = t >> 5;
    const int d0 = tx * 4, mb = ty * 8;
    float acc[8][4];
    #pragma unroll
    for (int i = 0; i < 8; ++i)
        #pragma unroll
        for (int j = 0; j < 4; ++j) acc[i][j] = 0.f;

    #pragma unroll 4
    for (int k = 0; k < 128; ++k) {
        float4 a0 = *(const float4*)(AT + k * 68 + mb);
        float4 a1 = *(const float4*)(AT + k * 68 + mb + 4);
        float4 bq = *(const float4*)(sfT + k * 128 + d0);
        float a[8] = {a0.x, a0.y, a0.z, a0.w, a1.x, a1.y, a1.z, a1.w};
        float b4[4] = {bq.x, bq.y, bq.z, bq.w};
        #pragma unroll
        for (int i = 0; i < 8; ++i)
            #pragma unroll
            for (int j = 0; j < 4; ++j)
                acc[i][j] = fmaf(a[i], b4[j], acc[i][j]);
    }

    #pragma unroll
    for (int i = 0; i < 8; ++i) {
        float4 o;
        float* ov = &o.x;
        #pragma unroll
        for (int j = 0; j < 4; ++j) {
            float v = acc[i][j];
            float r = v > 0.f ? v : 1.6732632423543772f * expm1f(v);
            ov[j] = 1.0507009873554805f * r;
        }
        *(float4*)(gbuf + (size_t)(m0 + mb + i) * 128 + d0) = o;
    }
}

__global__ __launch_bounds__(256) void k_agg_mono(const float* __restrict__ gbuf,
                                                  const float* __restrict__ aggw,
                                                  float* __restrict__ out)
{
    const int m0 = blockIdx.x * 64;
    const int t  = threadIdx.x;
    __shared__ __align__(16) float AT[128 * 68];

    const int tx = t & 31, ty = t >> 5;
    const int d0 = tx * 4, mb = ty * 8;
    float acc[8][4];
    #pragma unroll
    for (int i = 0; i < 8; ++i)
        #pragma unroll
        for (int j = 0; j < 4; ++j) acc[i][j] = 0.f;

    for (int kc = 0; kc < 8; ++kc) {
        __syncthreads();
        #pragma unroll
        for (int i = 0; i < 32; ++i) {
            int flat = i * 256 + t;
            int mm = flat >> 7, kk = flat & 127;
            AT[kk * 68 + mm] = gbuf[(size_t)(m0 + mm) * 1024 + kc * 128 + kk];
        }
        __syncthreads();
        #pragma unroll 4
        for (int kk = 0; kk < 128; ++kk) {
            float4 a0 = *(const float4*)(AT + kk * 68 + mb);
            float4 a1 = *(const float4*)(AT + kk * 68 + mb + 4);
            float4 bq = *(const float4*)(aggw + (size_t)(kc * 128 + kk) * 128 + d0);
            float a[8] = {a0.x, a0.y, a0.z, a0.w, a1.x, a1.y, a1.z, a1.w};
            float b4[4] = {bq.x, bq.y, bq.z, bq.w};
            #pragma unroll
            for (int i = 0; i < 8; ++i)
                #pragma unroll
                for (int j = 0; j < 4; ++j)
                    acc[i][j] = fmaf(a[i], b4[j], acc[i][j]);
        }
    }

    #pragma unroll
    for (int i = 0; i < 8; ++i) {
        float s = acc[i][0] * acc[i][0] + acc[i][1] * acc[i][1]
                + acc[i][2] * acc[i][2] + acc[i][3] * acc[i][3];
        #pragma unroll
        for (int m = 16; m; m >>= 1) s += __shfl_xor(s, m);
        const float inv = 1.f / fmaxf(sqrtf(s), 1e-12f);
        float4 o = {acc[i][0] * inv, acc[i][1] * inv, acc[i][2] * inv, acc[i][3] * inv};
        *(float4*)(out + (size_t)(m0 + mb + i) * 128 + d0) = o;
    }
}

extern "C" void kernel_launch(void* const* d_in, const int* in_sizes, int n_in,
                              void* d_out, int out_size, void* d_ws, size_t ws_size,
                              hipStream_t stream)
{
    const float* x   = (const float*)d_in[0];
    const float* kp  = (const float*)d_in[1];
    const float* w1  = (const float*)d_in[2];
    const float* b1  = (const float*)d_in[3];
    const float* w2  = (const float*)d_in[4];
    const float* b2  = (const float*)d_in[5];
    const float* sfw = (const float*)d_in[6];
    const float* agg = (const float*)d_in[7];
    float* out = (float*)d_out;

    if (ws_size < WS_MIN) return;

    char*  ws    = (char*)d_ws;
    float* sfT   = (float*)(ws + OFF_SFT);
    unsigned short* w1B  = (unsigned short*)(ws + OFF_W1T);  // reuses w1T slot
    unsigned short* xclb = (unsigned short*)(ws + OFF_XCL);  // bf16 NHWC x
    unsigned short* sfB  = (unsigned short*)(ws + OFF_SFB);
    unsigned short* agB  = (unsigned short*)(ws + OFF_AGB);

    if (ws_size >= WS_FULL) {
        k_trprep<<<5448, 256, 0, stream>>>(x, xclb, sfw, w1, agg, sfB, agB, w1B);
        k_mega  <<<NKP / 16, 256, 0, stream>>>(xclb, kp, w1B, b1, w2, b2, sfB, agB, out);
    } else {
        float* feats = (float*)ws;
        k_prep_legacy<<<64, 256, 0, stream>>>(sfw, sfT);
        k_sample   <<<NKP, 128, 0, stream>>>(x, kp, w1, b1, w2, b2, feats);
        k_sf_legacy<<<2000, 256, 0, stream>>>(feats, sfT);
        k_agg_mono <<<250,  256, 0, stream>>>(feats, agg, out);
    }
}

// Round 11
// 288.043 us; speedup vs baseline: 1.1189x; 1.0097x over previous
//
#include <hip/hip_runtime.h>
#include <cstdint>
#include <cmath>

#define BB   4
#define NK   4000
#define NKP  (BB*NK)      // 16000 keypoints total
#define CH   128
#define HH   240
#define WW   320
#define HWSZ (HH*WW)
#define NPOS 8

typedef __attribute__((ext_vector_type(8))) short short8;
typedef __attribute__((ext_vector_type(8))) unsigned short ushort8;
typedef __attribute__((ext_vector_type(4))) float f32x4;

// ws layout (bytes):
//   sfT      : 65,536  @ 65,536,000  [legacy]
//   w1B      : 36,864  @ 65,601,536  [bf16 MFMA-packed conv weights; reuses w1T slot]
//   xclb     : bf16 NHWC x, 78,643,200 @ 65,675,264
//   sfB      : 32,768  @ 222,961,664  [bf16 MFMA-packed sf_w^T]
//   agB      : 262,144 @ 222,994,432  [bf16 MFMA-packed agg_w]
static constexpr size_t OFF_POS  = 32768000;
static constexpr size_t OFF_SFT  = 65536000;
static constexpr size_t OFF_W1T  = 65601536;
static constexpr size_t OFF_XCL  = 65675264;
static constexpr size_t OFF_SFB  = 222961664;
static constexpr size_t OFF_AGB  = 222994432;
static constexpr size_t WS_FULL  = 223256576;
static constexpr size_t WS_MIN   = 65675264;

__device__ __forceinline__ unsigned short f2bf(float f) {   // RNE
    unsigned int u = __float_as_uint(f);
    u += 0x7fff + ((u >> 16) & 1);
    return (unsigned short)(u >> 16);
}
__device__ __forceinline__ float bf2f(unsigned short u) {
    return __uint_as_float((unsigned)u << 16);
}

// ---------------- K0: merged NCHW->NHWC transpose + weight prep ----------------
// Transpose retile (6th and final k_tr experiment): 128ch x 256px tile so each
// wave64 read = 1 KB contiguous from ONE channel row (1 DRAM page/instruction,
// 4x longer per-page runs). Prior configs all mixed 2-4 pages per instruction.
// bf16 conversion moved to read phase (same RNE on same values -> bit-identical).
// LDS bf16 [256][129] = 66 KB, 2 blocks/CU (occupancy proven irrelevant, r1).
__global__ __launch_bounds__(256) void k_trprep(
    const float* __restrict__ x,   unsigned short* __restrict__ xclb,
    const float* __restrict__ sfw, const float* __restrict__ w1,
    const float* __restrict__ aggw,
    unsigned short* __restrict__ sfB, unsigned short* __restrict__ agB,
    unsigned short* __restrict__ w1B)
{
    const int t = threadIdx.x;
    __shared__ unsigned short tile16[256 * 129];   // 66,048 B

    if (blockIdx.x < 1200) {
        const int b  = blockIdx.x / 300;
        const int p0 = (blockIdx.x % 300) * 256;
        #pragma unroll
        for (int i = 0; i < 32; ++i) {
            int flat = i * 256 + t;          // 0..8191
            int c  = flat >> 6;              // 0..127
            int p4 = flat & 63;              // 0..63
            float4 v = *(const float4*)(x + ((size_t)(b * 128 + c)) * HWSZ + p0 + p4 * 4);
            tile16[(p4 * 4 + 0) * 129 + c] = f2bf(v.x);
            tile16[(p4 * 4 + 1) * 129 + c] = f2bf(v.y);
            tile16[(p4 * 4 + 2) * 129 + c] = f2bf(v.z);
            tile16[(p4 * 4 + 3) * 129 + c] = f2bf(v.w);
        }
        __syncthreads();
        #pragma unroll
        for (int j = 0; j < 16; ++j) {
            int flat = j * 256 + t;          // 0..4095
            int p  = flat >> 4;              // 0..255
            int c8 = flat & 15;              // 0..15
            ushort8 o;
            #pragma unroll
            for (int k = 0; k < 8; ++k)
                o[k] = tile16[p * 129 + c8 * 8 + k];
            *(ushort8*)(xclb + ((size_t)b * HWSZ + p0 + p) * CH + c8 * 8) = o;
        }
    } else {
        int id = (blockIdx.x - 1200) * 256 + t;   // 0..165887
        if (id < 16384) {
            int idx = id;
            int j = idx & 7, lane = (idx >> 3) & 63, nt = (idx >> 9) & 7, kc32 = (idx >> 12) & 3;
            int k = kc32 * 32 + (lane >> 4) * 8 + j;
            int n = nt * 16 + (lane & 15);
            sfB[idx] = f2bf(sfw[n * 128 + k]);     // B[c][d] = sf_w[d][c]
        } else if (id < 16384 + 131072) {
            int idx = id - 16384;
            int local = idx & 16383, kc = idx >> 14;
            int j = local & 7, lane = (local >> 3) & 63, nt = (local >> 9) & 7, kc32 = (local >> 12) & 3;
            int k = kc * 128 + kc32 * 32 + (lane >> 4) * 8 + j;
            int n = nt * 16 + (lane & 15);
            agB[idx] = f2bf(aggw[(size_t)k * 128 + n]);
        } else if (id < 16384 + 131072 + 18432) {
            // w1B: B-frag layout (same convention as sfB): elem e -> lane l,
            // k = q*32 + (l>>4)*8 + j over K=1152 (order h,px,c), col o = l&15
            int e = id - (16384 + 131072);
            int j = e & 7, l = (e >> 3) & 63, q = e >> 9;      // q: 0..35
            int k = q * 32 + ((l >> 4) & 3) * 8 + j;           // 0..1151
            int o = l & 15;
            int h = k / 384, rem = k % 384;
            int px = rem >> 7, c = rem & 127;
            w1B[e] = f2bf(w1[o * 1152 + c * 9 + (h * 3 + px)]);
        }
    }
}

// ---------------- K1: mega-fused keypoint pipeline (4 blocks/CU) ----------------
// 16 kp / block, grid 1000, all co-resident (r9 win: single residency round).
//   A: stage full 3x3 patches bf16 (one shot, 9 loads in flight) ->
//      conv as 36x mfma 16x16x32 ([16kp x 1152] @ w1B) -> relu -> MLP -> posl
//      (replaces ~3.5K scalar VALU/thread; only new rounding = w1 -> bf16)
//   B: direct-fragment bilinear gather -> sf MFMA -> selu -> Gl (swizzled)
//   C: agg MFMA (K=1024) -> L2 normalize -> out
// LDS 39,424 B <= 40,960 (160KiB/4).
__global__ __launch_bounds__(256, 4) void k_mega(
    const unsigned short* __restrict__ xclb, const float* __restrict__ kp,
    const unsigned short* __restrict__ w1B, const float* __restrict__ b1,
    const float* __restrict__ w2,  const float* __restrict__ b2,
    const unsigned short* __restrict__ sfB,
    const unsigned short* __restrict__ agB,
    float* __restrict__ out)
{
    const int t  = threadIdx.x;
    const int n0 = blockIdx.x * 16;
    const int bi = n0 / NK;              // uniform per block (NK % 16 == 0)
    const int w  = t >> 6, l = t & 63;
    const int fr = l & 15, fq = l >> 4;

    __shared__ __align__(16) char U[37120];
    unsigned short* plb = (unsigned short*)U;    // [16][1160] bf16 37120 B (A)
    char*  GlB = U;                              // [128 x 256B]  32768 B (B,C)
    float* Dl = (float*)U;                       // [16*132] f32   8448 B (C)
    __shared__ float  o1l[16 * 16];
    __shared__ float  kwl[16 * 2];
    __shared__ int2   cxyl[16];
    __shared__ float2 posl[128];

    // ================= phase A: patches -> conv MFMA -> MLP =================
    if (t < 16) {
        const int n = n0 + t;
        float kx = kp[2 * n], ky = kp[2 * n + 1];
        float kwx = (kx * 0.5f + 0.5f) * (float)(WW - 1);
        float kwy = (ky * 0.5f + 0.5f) * (float)(HH - 1);
        kwl[t * 2 + 0] = kwx;
        kwl[t * 2 + 1] = kwy;
        int cx = (int)((float)((int)kwx) - 0.5f);
        int cy = (int)((float)((int)kwy) - 0.5f);
        cx = min(max(cx, 0), WW - 4);
        cy = min(max(cy, 0), HH - 4);
        cxyl[t] = make_int2(cx, cy);
    }
    __syncthreads();

    const unsigned short* xb = xclb + (size_t)bi * HWSZ * CH;

    // stage all 9 patch pixels x 128 ch per kp, K-order (h, px, c), raw bf16
    #pragma unroll
    for (int i = 0; i < 9; ++i) {
        int idx = i * 256 + t;           // 0..2303
        int kk = idx / 144, rr = idx % 144;
        int oe = rr * 8;                 // elem offset 0..1144
        int h = oe / 384, rem = oe % 384;
        int px = rem >> 7, c0 = rem & 127;
        int2 c = cxyl[kk];
        *(ushort8*)&plb[kk * 1160 + oe] =
            *(const ushort8*)(xb + ((size_t)(c.y + h) * WW + (c.x + px)) * CH + c0);
    }
    __syncthreads();

    // conv: out[16kp x 16o] = patches @ w1B, 36 MFMA (redundant per wave)
    {
        f32x4 ca;
        #pragma unroll
        for (int r = 0; r < 4; ++r) ca[r] = 0.f;
        #pragma unroll 4
        for (int q = 0; q < 36; ++q) {
            short8 a = *(const short8*)(plb + fr * 1160 + q * 32 + fq * 8);
            short8 b = *(const short8*)(w1B + (size_t)(q * 64 + l) * 8);
            ca = __builtin_amdgcn_mfma_f32_16x16x32_bf16(a, b, ca, 0, 0, 0);
        }
        if (w == 0) {
            #pragma unroll
            for (int r = 0; r < 4; ++r)
                o1l[(fq * 4 + r) * 16 + fr] = fmaxf(ca[r] + b1[fr], 0.f);
        }
    }
    __syncthreads();

    if (t < 128) {
        const int kk = t >> 3, j = t & 7;
        float sx = b2[j], sy = b2[8 + j];
        #pragma unroll
        for (int i = 0; i < 16; ++i) {
            float v = o1l[kk * 16 + i];
            sx = fmaf(v, w2[j * 16 + i], sx);
            sy = fmaf(v, w2[(8 + j) * 16 + i], sy);
        }
        sx = fminf(fmaxf(sx, -80.f), 80.f);
        sy = fminf(fmaxf(sy, -80.f), 80.f);
        posl[kk * 8 + j] = make_float2(kwl[kk * 2 + 0] + sx, kwl[kk * 2 + 1] + sy);
    }
    __syncthreads();

    // ====== phase B: direct-fragment gather + sf MFMA + selu -> Gl ======
    for (int chunk = 0; chunk < 2; ++chunk) {
        const int arow = chunk * 64 + w * 16 + fr;   // sample row this lane owns
        float2 P = posl[arow];
        const float x0 = floorf(P.x), y0 = floorf(P.y);
        const float wx = P.x - x0, wy = P.y - y0;
        const unsigned short* cp[4];
        float cw[4];
        #pragma unroll
        for (int dy = 0; dy < 2; ++dy) {
            const float yc = y0 + (float)dy;
            const bool vy = (yc >= 0.f) && (yc <= (float)(HH - 1));
            const int  yi = (int)fminf(fmaxf(yc, 0.f), (float)(HH - 1));
            const float wyv = dy ? wy : (1.f - wy);
            #pragma unroll
            for (int dx = 0; dx < 2; ++dx) {
                const float xc = x0 + (float)dx;
                const bool vx = (xc >= 0.f) && (xc <= (float)(WW - 1));
                const int  xi = (int)fminf(fmaxf(xc, 0.f), (float)(WW - 1));
                cp[dy * 2 + dx] = xb + ((size_t)yi * WW + xi) * CH;
                cw[dy * 2 + dx] = (vx && vy) ? (dx ? wx : (1.f - wx)) * wyv : 0.f;
            }
        }

        short8 a[4];
        #pragma unroll
        for (int q = 0; q < 4; ++q) {
            const int ch = q * 32 + fq * 8;
            ushort8 c0 = *(const ushort8*)(cp[0] + ch);
            ushort8 c1 = *(const ushort8*)(cp[1] + ch);
            ushort8 c2 = *(const ushort8*)(cp[2] + ch);
            ushort8 c3 = *(const ushort8*)(cp[3] + ch);
            short8 av;
            #pragma unroll
            for (int j = 0; j < 8; ++j) {
                float s = fmaf(bf2f(c0[j]), cw[0], 0.f);   // same corner order
                s = fmaf(bf2f(c1[j]), cw[1], s);
                s = fmaf(bf2f(c2[j]), cw[2], s);
                s = fmaf(bf2f(c3[j]), cw[3], s);
                av[j] = (short)f2bf(s);
            }
            a[q] = av;
        }

        f32x4 acc[8];
        #pragma unroll
        for (int nt = 0; nt < 8; ++nt)
            #pragma unroll
            for (int r = 0; r < 4; ++r) acc[nt][r] = 0.f;

        #pragma unroll 2
        for (int nt = 0; nt < 8; ++nt) {
            short8 b[4];
            #pragma unroll
            for (int q = 0; q < 4; ++q)
                b[q] = *(const short8*)(sfB + ((size_t)(q * 8 + nt) * 64 + l) * 8);
            #pragma unroll
            for (int q = 0; q < 4; ++q)
                acc[nt] = __builtin_amdgcn_mfma_f32_16x16x32_bf16(a[q], b[q], acc[nt], 0, 0, 0);
        }

        if (chunk == 0) __syncthreads();   // plb fully dead (conv done pre-MLP barriers)
        #pragma unroll
        for (int nt = 0; nt < 8; ++nt)
            #pragma unroll
            for (int r = 0; r < 4; ++r) {
                float v = acc[nt][r];
                // selu; __expf ok: result rounded to bf16 (quantum ~4e-3 rel).
                float e = v > 0.f ? v : 1.6732632423543772f * (__expf(v) - 1.f);
                const int row = chunk * 64 + w * 16 + fq * 4 + r;
                unsigned byte = (unsigned)(row * 256 + (nt * 16 + fr) * 2);
                byte ^= ((unsigned)((row >> 3) & 7)) << 4;
                *(unsigned short*)(GlB + byte) = f2bf(1.0507009873554805f * e);
            }
    }
    __syncthreads();

    // ================= phase C: agg MFMA + normalize =================
    f32x4 acc2[2];
    #pragma unroll
    for (int i = 0; i < 2; ++i)
        #pragma unroll
        for (int r = 0; r < 4; ++r) acc2[i][r] = 0.f;

    const int nt0 = w * 2;
    #pragma unroll 4
    for (int kk = 0; kk < 32; ++kk) {
        const int row = fr * 8 + (kk >> 2);            // n_local*8 + p
        unsigned byte = (unsigned)(row * 256 + ((kk & 3) * 32 + fq * 8) * 2);
        byte ^= ((unsigned)((row >> 3) & 7)) << 4;
        short8 a2 = *(const short8*)(GlB + byte);
        #pragma unroll
        for (int i = 0; i < 2; ++i) {
            short8 b2 = *(const short8*)(agB + (size_t)(kk >> 2) * 16384 +
                ((size_t)(((kk & 3) * 8 + nt0 + i) * 64 + l)) * 8);
            acc2[i] = __builtin_amdgcn_mfma_f32_16x16x32_bf16(a2, b2, acc2[i], 0, 0, 0);
        }
    }

    __syncthreads();                 // all GlB reads done before Dl (aliases GlB)
    #pragma unroll
    for (int i = 0; i < 2; ++i)
        #pragma unroll
        for (int r = 0; r < 4; ++r)
            Dl[(fq * 4 + r) * 132 + w * 32 + i * 16 + fr] = acc2[i][r];
    __syncthreads();

    {
        const int row = t >> 4, seg = t & 15;
        const float* dr = Dl + row * 132 + seg * 8;
        float4 d0 = *(const float4*)(dr);
        float4 d1 = *(const float4*)(dr + 4);
        float s = d0.x*d0.x + d0.y*d0.y + d0.z*d0.z + d0.w*d0.w
                + d1.x*d1.x + d1.y*d1.y + d1.z*d1.z + d1.w*d1.w;
        #pragma unroll
        for (int m = 1; m < 16; m <<= 1) s += __shfl_xor(s, m);
        const float inv = 1.f / fmaxf(sqrtf(s), 1e-12f);
        float* op = out + (size_t)(n0 + row) * 128 + seg * 8;
        float4 o0 = {d0.x*inv, d0.y*inv, d0.z*inv, d0.w*inv};
        float4 o1 = {d1.x*inv, d1.y*inv, d1.z*inv, d1.w*inv};
        *(float4*)(op)     = o0;
        *(float4*)(op + 4) = o1;
    }
}

// ================= legacy fallback path (small ws) =================
__global__ __launch_bounds__(256) void k_prep_legacy(const float* __restrict__ sfw,
                                                     float* __restrict__ sfT)
{
    int id = blockIdx.x * 256 + threadIdx.x;
    if (id < 16384) {
        int cc = id >> 7, dd = id & 127;
        sfT[cc * 128 + dd] = sfw[dd * 128 + cc];
    }
}

__global__ __launch_bounds__(128) void k_sample(
    const float* __restrict__ x,  const float* __restrict__ kp,
    const float* __restrict__ w1, const float* __restrict__ b1,
    const float* __restrict__ w2, const float* __restrict__ b2,
    float* __restrict__ feats)
{
    const int n  = blockIdx.x;
    const int bi = n / NK;
    const int t  = threadIdx.x;

    __shared__ __align__(16) float patch[CH * 9];
    __shared__ float red[16 * 8];
    __shared__ float o1[16];
    __shared__ float offv[16];

    const float kx  = kp[(size_t)n * 2 + 0];
    const float ky  = kp[(size_t)n * 2 + 1];
    const float kwx = (kx * 0.5f + 0.5f) * (float)(WW - 1);
    const float kwy = (ky * 0.5f + 0.5f) * (float)(HH - 1);
    const int kwlx = (int)kwx;
    const int kwly = (int)kwy;
    int cx = (int)((float)kwlx - 0.5f);
    int cy = (int)((float)kwly - 0.5f);
    cx = min(max(cx, 0), WW - 1 - 3);
    cy = min(max(cy, 0), HH - 1 - 3);

    const float* xb = x + ((size_t)bi * CH + t) * HWSZ;
    {
        const float* p0 = xb + cy * WW + cx;
        #pragma unroll
        for (int i = 0; i < 3; ++i) {
            patch[t * 9 + i * 3 + 0] = p0[i * WW + 0];
            patch[t * 9 + i * 3 + 1] = p0[i * WW + 1];
            patch[t * 9 + i * 3 + 2] = p0[i * WW + 2];
        }
    }
    __syncthreads();
    {
        const int o = t & 15, g = t >> 4;
        const float4* wp = (const float4*)(w1 + o * 1152 + g * 144);
        const float4* pp = (const float4*)(patch + g * 144);
        float s = 0.f;
        #pragma unroll
        for (int q = 0; q < 36; ++q) {
            float4 wv = wp[q];
            float4 pv = pp[q];
            s = fmaf(wv.x, pv.x, fmaf(wv.y, pv.y, fmaf(wv.z, pv.z, fmaf(wv.w, pv.w, s))));
        }
        red[o * 8 + g] = s;
    }
    __syncthreads();
    if (t < 16) {
        float s = b1[t];
        #pragma unroll
        for (int g = 0; g < 8; ++g) s += red[t * 8 + g];
        o1[t] = fmaxf(s, 0.f);
    }
    __syncthreads();
    if (t < 16) {
        float s = b2[t];
        #pragma unroll
        for (int j = 0; j < 16; ++j) s = fmaf(o1[j], w2[t * 16 + j], s);
        offv[t] = fminf(fmaxf(s, -80.f), 80.f);
    }
    __syncthreads();

    #pragma unroll
    for (int p = 0; p < NPOS; ++p) {
        const float px = kwx + offv[p];
        const float py = kwy + offv[8 + p];
        const float x0 = floorf(px), y0 = floorf(py);
        const float wx = px - x0, wy = py - y0;
        float acc = 0.f;
        #pragma unroll
        for (int dy = 0; dy < 2; ++dy) {
            const float yc = y0 + (float)dy;
            const bool vy = (yc >= 0.f) && (yc <= (float)(HH - 1));
            const int  yi = (int)fminf(fmaxf(yc, 0.f), (float)(HH - 1));
            const float wyv = dy ? wy : (1.f - wy);
            #pragma unroll
            for (int dx = 0; dx < 2; ++dx) {
                const float xc = x0 + (float)dx;
                const bool vx = (xc >= 0.f) && (xc <= (float)(WW - 1));
                const int  xi = (int)fminf(fmaxf(xc, 0.f), (float)(WW - 1));
                const float wxv = dx ? wx : (1.f - wx);
                float v = xb[yi * WW + xi];
                v = (vx && vy) ? v : 0.f;
                acc = fmaf(v, wxv * wyv, acc);
            }
        }
        feats[((size_t)n * 8 + p) * CH + t] = acc;
    }
}

__global__ __launch_bounds__(256) void k_sf_legacy(float* __restrict__ gbuf,
                                                   const float* __restrict__ sfT)
{
    const int m0 = blockIdx.x * 64;
    const int t  = threadIdx.x;
    __shared__ __align__(16) float AT[128 * 68];

    #pragma unroll
    for (int i = 0; i < 32; ++i) {
        int flat = i * 256 + t;
        int mm = flat >> 7, kk = flat & 127;
        AT[kk * 68 + mm] = gbuf[(size_t)(m0 + mm) * 128 + kk];
    }
    __syncthreads();

    const int tx = t & 31, ty = t >> 5;
    const int d0 = tx * 4, mb = ty * 8;
    float acc[8][4];
    #pragma unroll
    for (int i = 0; i < 8; ++i)
        #pragma unroll
        for (int j = 0; j < 4; ++j) acc[i][j] = 0.f;

    #pragma unroll 4
    for (int k = 0; k < 128; ++k) {
        float4 a0 = *(const float4*)(AT + k * 68 + mb);
        float4 a1 = *(const float4*)(AT + k * 68 + mb + 4);
        float4 bq = *(const float4*)(sfT + k * 128 + d0);
        float a[8] = {a0.x, a0.y, a0.z, a0.w, a1.x, a1.y, a1.z, a1.w};
        float b4[4] = {bq.x, bq.y, bq.z, bq.w};
        #pragma unroll
        for (int i = 0; i < 8; ++i)
            #pragma unroll
            for (int j = 0; j < 4; ++j)
                acc[i][j] = fmaf(a[i], b4[j], acc[i][j]);
    }

    #pragma unroll
    for (int i = 0; i < 8; ++i) {
        float4 o;
        float* ov = &o.x;
        #pragma unroll
        for (int j = 0; j < 4; ++j) {
            float v = acc[i][j];
            float r = v > 0.f ? v : 1.6732632423543772f * expm1f(v);
            ov[j] = 1.0507009873554805f * r;
        }
        *(float4*)(gbuf + (size_t)(m0 + mb + i) * 128 + d0) = o;
    }
}

__global__ __launch_bounds__(256) void k_agg_mono(const float* __restrict__ gbuf,
                                                  const float* __restrict__ aggw,
                                                  float* __restrict__ out)
{
    const int m0 = blockIdx.x * 64;
    const int t  = threadIdx.x;
    __shared__ __align__(16) float AT[128 * 68];

    const int tx = t & 31, ty = t >> 5;
    const int d0 = tx * 4, mb = ty * 8;
    float acc[8][4];
    #pragma unroll
    for (int i = 0; i < 8; ++i)
        #pragma unroll
        for (int j = 0; j < 4; ++j) acc[i][j] = 0.f;

    for (int kc = 0; kc < 8; ++kc) {
        __syncthreads();
        #pragma unroll
        for (int i = 0; i < 32; ++i) {
            int flat = i * 256 + t;
            int mm = flat >> 7, kk = flat & 127;
            AT[kk * 68 + mm] = gbuf[(size_t)(m0 + mm) * 1024 + kc * 128 + kk];
        }
        __syncthreads();
        #pragma unroll 4
        for (int kk = 0; kk < 128; ++kk) {
            float4 a0 = *(const float4*)(AT + kk * 68 + mb);
            float4 a1 = *(const float4*)(AT + kk * 68 + mb + 4);
            float4 bq = *(const float4*)(aggw + (size_t)(kc * 128 + kk) * 128 + d0);
            float a[8] = {a0.x, a0.y, a0.z, a0.w, a1.x, a1.y, a1.z, a1.w};
            float b4[4] = {bq.x, bq.y, bq.z, bq.w};
            #pragma unroll
            for (int i = 0; i < 8; ++i)
                #pragma unroll
                for (int j = 0; j < 4; ++j)
                    acc[i][j] = fmaf(a[i], b4[j], acc[i][j]);
        }
    }

    #pragma unroll
    for (int i = 0; i < 8; ++i) {
        float s = acc[i][0] * acc[i][0] + acc[i][1] * acc[i][1]
                + acc[i][2] * acc[i][2] + acc[i][3] * acc[i][3];
        #pragma unroll
        for (int m = 16; m; m >>= 1) s += __shfl_xor(s, m);
        const float inv = 1.f / fmaxf(sqrtf(s), 1e-12f);
        float4 o = {acc[i][0] * inv, acc[i][1] * inv, acc[i][2] * inv, acc[i][3] * inv};
        *(float4*)(out + (size_t)(m0 + mb + i) * 128 + d0) = o;
    }
}

extern "C" void kernel_launch(void* const* d_in, const int* in_sizes, int n_in,
                              void* d_out, int out_size, void* d_ws, size_t ws_size,
                              hipStream_t stream)
{
    const float* x   = (const float*)d_in[0];
    const float* kp  = (const float*)d_in[1];
    const float* w1  = (const float*)d_in[2];
    const float* b1  = (const float*)d_in[3];
    const float* w2  = (const float*)d_in[4];
    const float* b2  = (const float*)d_in[5];
    const float* sfw = (const float*)d_in[6];
    const float* agg = (const float*)d_in[7];
    float* out = (float*)d_out;

    if (ws_size < WS_MIN) return;

    char*  ws    = (char*)d_ws;
    float* sfT   = (float*)(ws + OFF_SFT);
    unsigned short* w1B  = (unsigned short*)(ws + OFF_W1T);  // reuses w1T slot
    unsigned short* xclb = (unsigned short*)(ws + OFF_XCL);  // bf16 NHWC x
    unsigned short* sfB  = (unsigned short*)(ws + OFF_SFB);
    unsigned short* agB  = (unsigned short*)(ws + OFF_AGB);

    if (ws_size >= WS_FULL) {
        k_trprep<<<1848, 256, 0, stream>>>(x, xclb, sfw, w1, agg, sfB, agB, w1B);
        k_mega  <<<NKP / 16, 256, 0, stream>>>(xclb, kp, w1B, b1, w2, b2, sfB, agB, out);
    } else {
        float* feats = (float*)ws;
        k_prep_legacy<<<64, 256, 0, stream>>>(sfw, sfT);
        k_sample   <<<NKP, 128, 0, stream>>>(x, kp, w1, b1, w2, b2, feats);
        k_sf_legacy<<<2000, 256, 0, stream>>>(feats, sfT);
        k_agg_mono <<<250,  256, 0, stream>>>(feats, agg, out);
    }
}